// Round 16
// baseline (119.113 us; speedup 1.0000x reference)
//
#include <hip/hip_runtime.h>
#include <hip/hip_bf16.h>

#define TT   2048   // B*S tokens
#define HH   2048   // hidden dim
#define SEQ  1024
#define NHQ  16
#define NKVH 8
#define HDD  128

typedef __attribute__((ext_vector_type(8))) short short8;
typedef __attribute__((ext_vector_type(4))) float f32x4;
typedef __attribute__((ext_vector_type(4))) int int4v;
typedef _Float16 half8 __attribute__((ext_vector_type(8)));

static __device__ __forceinline__ unsigned short f2h(float f) {
  union { _Float16 h; unsigned short u; } c;
  c.h = (_Float16)f;
  return c.u;
}
static __device__ __forceinline__ half8 s2h(short8 v) {
  union { short8 s; half8 h; } c;
  c.s = v;
  return c.h;
}

#define GLD_LDS16(gp, lp)                                                        \
  __builtin_amdgcn_global_load_lds(                                              \
      (const __attribute__((address_space(1))) void*)(const void*)(gp),          \
      (__attribute__((address_space(3))) void*)(void*)(lp), 16, 0, 0)

// ---------------------------------------------------------------------------
// K1: fused act_quant(x) + weight |w| partial sums, one dispatch.
// ---------------------------------------------------------------------------
__global__ __launch_bounds__(256) void k_quant_stats(const float* __restrict__ x,
                                                     signed char* __restrict__ xq,
                                                     float* __restrict__ as_inv,
                                                     const float* __restrict__ wq,
                                                     const float* __restrict__ wk,
                                                     const float* __restrict__ wv,
                                                     const float* __restrict__ wo,
                                                     double* __restrict__ part) {
  int tid = threadIdx.x;
  int wave = tid >> 6, lane = tid & 63;
  __shared__ double redd[256];
  __shared__ float wred[4];

  if (blockIdx.x < 2048) {
    int row = blockIdx.x;
    const float4* xr4 = (const float4*)(x + (size_t)row * HH);
    float4 a = xr4[tid * 2], b = xr4[tid * 2 + 1];
    float am = fmaxf(fmaxf(fmaxf(fabsf(a.x), fabsf(a.y)), fmaxf(fabsf(a.z), fabsf(a.w))),
                     fmaxf(fmaxf(fabsf(b.x), fabsf(b.y)), fmaxf(fabsf(b.z), fabsf(b.w))));
#pragma unroll
    for (int o = 32; o; o >>= 1) am = fmaxf(am, __shfl_xor(am, o));
    if (lane == 0) wred[wave] = am;
    __syncthreads();
    am = fmaxf(fmaxf(wred[0], wred[1]), fmaxf(wred[2], wred[3]));
    am = fmaxf(am, 1e-5f);
    if (tid == 0) as_inv[row] = am / 127.f;
    float scale = 127.f / am;
    float vals[8] = {a.x, a.y, a.z, a.w, b.x, b.y, b.z, b.w};
    unsigned int u0 = 0, u1 = 0;
#pragma unroll
    for (int j = 0; j < 4; ++j) {
      int q = (int)fminf(fmaxf(rintf(vals[j] * scale), -128.f), 127.f);
      u0 |= (unsigned int)(q & 255) << (8 * j);
    }
#pragma unroll
    for (int j = 0; j < 4; ++j) {
      int q = (int)fminf(fmaxf(rintf(vals[4 + j] * scale), -128.f), 127.f);
      u1 |= (unsigned int)(q & 255) << (8 * j);
    }
    uint2 uu; uu.x = u0; uu.y = u1;
    ((uint2*)(xq + (size_t)row * HH))[tid] = uu;
  } else {
    int idx = blockIdx.x - 2048;
    int wid = idx >> 8, sub = idx & 255;
    const float* w = (wid == 0) ? wq : (wid == 1) ? wk : (wid == 2) ? wv : wo;
    int nq = ((wid == 0 || wid == 3) ? 4194304 : 2097152) >> 2;
    double s = 0.0;
    for (int i = sub * 256 + tid; i < nq; i += 256 * 256) {
      float4 v = ((const float4*)w)[i];
      s += (double)fabsf(v.x) + (double)fabsf(v.y) + (double)fabsf(v.z) + (double)fabsf(v.w);
    }
    redd[tid] = s;
    __syncthreads();
    for (int st = 128; st > 0; st >>= 1) {
      if (tid < st) redd[tid] += redd[tid + st];
      __syncthreads();
    }
    if (tid == 0) part[wid * 256 + sub] = redd[0];
  }
}

// ---------------------------------------------------------------------------
// K3: ternary weight quant -> int8 for wq,wk,wv. Block 0 publishes wsc.
// ---------------------------------------------------------------------------
__global__ __launch_bounds__(256) void k_wquant_all(const float* __restrict__ wq,
                                                    const float* __restrict__ wk,
                                                    const float* __restrict__ wv,
                                                    signed char* __restrict__ wqk,
                                                    signed char* __restrict__ wvt,
                                                    const double* __restrict__ part,
                                                    float* __restrict__ wsc) {
  int tid = threadIdx.x;
  int wave = tid >> 6, lane = tid & 63;
  __shared__ double wred[4][4];
  __shared__ float s_wsc[4];
  const double nvals[4] = {4194304.0, 2097152.0, 2097152.0, 4194304.0};
#pragma unroll
  for (int w = 0; w < 4; ++w) {
    double s = part[w * 256 + tid];
#pragma unroll
    for (int o = 32; o; o >>= 1) s += __shfl_xor(s, o);
    if (lane == 0) wred[w][wave] = s;
  }
  __syncthreads();
  if (tid < 4) {
    double s = (wred[tid][0] + wred[tid][1]) + (wred[tid][2] + wred[tid][3]);
    float v = fmaxf((float)(s / nvals[tid]), 1e-5f);
    s_wsc[tid] = v;
    if (blockIdx.x == 0) wsc[tid] = v;
  }
  __syncthreads();
  float inv0 = 1.f / s_wsc[0], inv1 = 1.f / s_wsc[1], inv2 = 1.f / s_wsc[2];

  const int NQ = 2097152;   // wq(1048576) + wk(524288) + wv(524288) quads
  for (int qi = blockIdx.x * 256 + tid; qi < NQ; qi += gridDim.x * 256) {
    const float* src; signed char* dst; float inv; int off;
    if (qi < 1048576)      { src = wq; dst = wqk;           off = qi;           inv = inv0; }
    else if (qi < 1572864) { src = wk; dst = wqk + 4194304; off = qi - 1048576; inv = inv1; }
    else                   { src = wv; dst = wvt;           off = qi - 1572864; inv = inv2; }
    float4 v = ((const float4*)src)[off];
    unsigned int u = 0;
    float vv[4] = {v.x, v.y, v.z, v.w};
#pragma unroll
    for (int j = 0; j < 4; ++j) {
      int q = (int)fminf(fmaxf(rintf(vv[j] * inv), -1.f), 1.f);
      u |= (unsigned int)(q & 255) << (8 * j);
    }
    ((unsigned int*)dst)[off] = u;
  }
}

// ---------------------------------------------------------------------------
// K4: QKV i8 MFMA NT-GEMM, 128x128 tile, BK=128, 2-buffer stage-at-top
// pipeline, 8-way XOR swizzle, 512 blocks. (unchanged from round 13)
// ---------------------------------------------------------------------------
__global__ __launch_bounds__(256) void k_gemm_i8(const signed char* __restrict__ A0,
                                                 const signed char* __restrict__ B0,
                                                 const signed char* __restrict__ B1,
                                                 unsigned short* __restrict__ dh,
                                                 const float* __restrict__ asx,
                                                 const float* __restrict__ wsc,
                                                 const float* __restrict__ qn,
                                                 const float* __restrict__ kn,
                                                 const float* __restrict__ cs,
                                                 const float* __restrict__ sn,
                                                 unsigned short* __restrict__ qf,
                                                 unsigned short* __restrict__ kf) {
  const int K = HH;
  __shared__ signed char As[2][16384];   // [buf][128][128] swizzled rows
  __shared__ signed char Bs[2][16384];
  int tid = threadIdx.x;
  int wave = tid >> 6, lane = tid & 63, l15 = lane & 15, g = lane >> 4;
  int wm = wave >> 1, wn = wave & 1;

  int gid = (blockIdx.x & 7) * 64 + (blockIdx.x >> 3);   // XCD chunk, 512 blocks
  const signed char *Ap, *Bp;
  int bm, bn, mode;
  if (gid < 384) { mode = 0; bm = (gid / 24) * 128; bn = (gid % 24) * 128; Ap = A0; Bp = B0; }
  else { mode = 1; int vid = gid - 384; bm = (vid >> 4) * 128; bn = (vid & 15) * 128; Ap = B1; Bp = A0; }

#define GSTAGE(K0, BUF)                                                               \
  {                                                                                   \
    _Pragma("unroll")                                                                 \
    for (int r = 0; r < 4; ++r) {                                                     \
      int c = r * 256 + tid;                                                          \
      int row = c >> 3;                                                               \
      int kk2 = ((c & 7) << 4) ^ ((row & 7) << 4);                                    \
      GLD_LDS16(Ap + (size_t)(bm + row) * K + (K0) + kk2, As[BUF] + c * 16);          \
      GLD_LDS16(Bp + (size_t)(bn + row) * K + (K0) + kk2, Bs[BUF] + c * 16);          \
    }                                                                                 \
  }

  int4v acc[4][4] = {};
  GSTAGE(0, 0);
  asm volatile("s_waitcnt vmcnt(0)" ::: "memory");
  __builtin_amdgcn_s_barrier();
  __builtin_amdgcn_sched_barrier(0);

  int buf = 0;
  for (int k0 = 0; k0 < K; k0 += 128) {
    bool more = (k0 + 128 < K);
    if (more) GSTAGE(k0 + 128, buf ^ 1);   // issued early; compute covers latency
#pragma unroll
    for (int ks = 0; ks < 2; ++ks) {
      int4v af[4], bf[4];
#pragma unroll
      for (int i = 0; i < 4; ++i) {
        int ra = wm * 64 + i * 16 + l15;
        af[i] = *(const int4v*)&As[buf][ra * 128 + ((ks * 64 + g * 16) ^ ((ra & 7) << 4))];
        int rb = (mode == 0) ? (wn * 32 + (i & 1) * 16 + (i >> 1) * 64 + l15)
                             : (wn * 64 + i * 16 + l15);
        bf[i] = *(const int4v*)&Bs[buf][rb * 128 + ((ks * 64 + g * 16) ^ ((rb & 7) << 4))];
      }
      __builtin_amdgcn_s_setprio(1);
#pragma unroll
      for (int mi = 0; mi < 4; ++mi)
#pragma unroll
        for (int ni = 0; ni < 4; ++ni)
          acc[mi][ni] = __builtin_amdgcn_mfma_i32_16x16x64_i8(af[mi], bf[ni], acc[mi][ni], 0, 0, 0);
      __builtin_amdgcn_s_setprio(0);
    }
    asm volatile("s_waitcnt vmcnt(0)" ::: "memory");
    __builtin_amdgcn_s_barrier();
    __builtin_amdgcn_sched_barrier(0);
    buf ^= 1;
  }
#undef GSTAGE

  if (mode == 0) {
    // fused rmsnorm + rope epilogue -> single fp16
    bool isq = (bn < 2048);
    int hh = isq ? (bn >> 7) : ((bn - 2048) >> 7);
    float wN = isq ? wsc[0] : wsc[1];
    float ps = isq ? 0.12751743075f : 1.0f;   // (1/sqrt(128))*log2(e) for q
    const float* nw = isq ? qn : kn;
    unsigned short* oh = isq ? qf : kf;
    int nhp = isq ? NHQ : NKVH;
    float* S = (float*)&As[0][0];        // reuse LDS: [2][128] f32
    __syncthreads();
#pragma unroll
    for (int mi = 0; mi < 4; ++mi) {
#pragma unroll
      for (int rr = 0; rr < 4; ++rr) {
        int tok = bm + wm * 64 + mi * 16 + 4 * g + rr;
        float rs = asx[tok] * wN;
        float ssum = 0.f;
#pragma unroll
        for (int ni = 0; ni < 4; ++ni) {
          float v = (float)acc[mi][ni][rr] * rs;
          ssum += v * v;
        }
        ssum += __shfl_xor(ssum, 1); ssum += __shfl_xor(ssum, 2);
        ssum += __shfl_xor(ssum, 4); ssum += __shfl_xor(ssum, 8);
        if (l15 == 0) S[wn * 128 + wm * 64 + mi * 16 + 4 * g + rr] = ssum;
      }
    }
    __syncthreads();
#pragma unroll
    for (int mi = 0; mi < 4; ++mi) {
#pragma unroll
      for (int rr = 0; rr < 4; ++rr) {
        int rloc = wm * 64 + mi * 16 + 4 * g + rr;
        int tok = bm + rloc;
        float rs = asx[tok] * wN;
        float inv = rsqrtf((S[rloc] + S[128 + rloc]) * (1.f / 128.f) + 1e-6f);
        int s = tok & (SEQ - 1);
        float nv[4];
#pragma unroll
        for (int ni = 0; ni < 4; ++ni) {
          int d = wn * 32 + (ni & 1) * 16 + (ni >> 1) * 64 + l15;
          nv[ni] = nw[d] * ((float)acc[mi][ni][rr] * rs) * inv;
        }
#pragma unroll
        for (int ni = 0; ni < 4; ++ni) {
          int d = wn * 32 + (ni & 1) * 16 + (ni >> 1) * 64 + l15;
          float oo = nv[ni ^ 2];
          float rh = (ni < 2) ? -oo : oo;
          float res = (nv[ni] * cs[s * 128 + d] + rh * sn[s * 128 + d]) * ps;
          size_t oi = ((size_t)tok * nhp + hh) * 128 + d;
          oh[oi] = f2h(res);
        }
      }
    }
  } else {   // mode 1: V fp16 transposed (crow=feature, ccol=token)
    float w2 = wsc[2];
#pragma unroll
    for (int mi = 0; mi < 4; ++mi) {
#pragma unroll
      for (int rr = 0; rr < 4; ++rr) {
        int crow = bm + wm * 64 + mi * 16 + 4 * g + rr;
#pragma unroll
        for (int ni = 0; ni < 4; ++ni) {
          int ccol = bn + wn * 64 + ni * 16 + l15;
          float v = (float)acc[mi][ni][rr] * asx[ccol] * w2;
          size_t ad = ((size_t)((ccol >> 10) * 1024 + crow)) * 1024 + (ccol & 1023);
          dh[ad] = f2h(v);
        }
      }
    }
  }
}

// ---------------------------------------------------------------------------
// K4b: O projection, 128x64 tiles, BK=128, 512 blocks, 2-buffer pipeline.
// (reverted to the round-14 configuration)
// ---------------------------------------------------------------------------
__global__ __launch_bounds__(256) void k_gemm_o(const signed char* __restrict__ A,
                                                const signed char* __restrict__ B,
                                                float* __restrict__ d0,
                                                const float* __restrict__ asx,
                                                const float* __restrict__ wsc) {
  const int K = HH;
  __shared__ signed char As[2][16384];   // [buf][128][128]
  __shared__ signed char Bs[2][8192];    // [buf][64][128]
  int tid = threadIdx.x;
  int wave = tid >> 6, lane = tid & 63, l15 = lane & 15, g = lane >> 4;
  int gid = (blockIdx.x & 7) * 64 + (blockIdx.x >> 3);
  int bm = (gid >> 5) * 128, bn = (gid & 31) * 64;

#define OSTAGE(K0, BUF)                                                               \
  {                                                                                   \
    _Pragma("unroll")                                                                 \
    for (int r = 0; r < 4; ++r) {                                                     \
      int c = r * 256 + tid;                                                          \
      int row = c >> 3;                                                               \
      int kk2 = ((c & 7) << 4) ^ ((row & 7) << 4);                                    \
      GLD_LDS16(A + (size_t)(bm + row) * K + (K0) + kk2, As[BUF] + c * 16);           \
    }                                                                                 \
    _Pragma("unroll")                                                                 \
    for (int r = 0; r < 2; ++r) {                                                     \
      int c = r * 256 + tid;                                                          \
      int row = c >> 3;                                                               \
      int kk2 = ((c & 7) << 4) ^ ((row & 7) << 4);                                    \
      GLD_LDS16(B + (size_t)(bn + row) * K + (K0) + kk2, Bs[BUF] + c * 16);           \
    }                                                                                 \
  }

  int4v acc[2][4] = {};
  OSTAGE(0, 0);
  asm volatile("s_waitcnt vmcnt(0)" ::: "memory");
  __builtin_amdgcn_s_barrier();
  __builtin_amdgcn_sched_barrier(0);

  int buf = 0;
  for (int k0 = 0; k0 < K; k0 += 128) {
    bool more = (k0 + 128 < K);
    if (more) OSTAGE(k0 + 128, buf ^ 1);
#pragma unroll
    for (int ks = 0; ks < 2; ++ks) {
      int4v af[2], bf[4];
#pragma unroll
      for (int i = 0; i < 2; ++i) {
        int ra = wave * 32 + i * 16 + l15;
        af[i] = *(const int4v*)&As[buf][ra * 128 + ((ks * 64 + g * 16) ^ ((ra & 7) << 4))];
      }
#pragma unroll
      for (int n = 0; n < 4; ++n) {
        int rb = n * 16 + l15;
        bf[n] = *(const int4v*)&Bs[buf][rb * 128 + ((ks * 64 + g * 16) ^ ((rb & 7) << 4))];
      }
      __builtin_amdgcn_s_setprio(1);
#pragma unroll
      for (int mi = 0; mi < 2; ++mi)
#pragma unroll
        for (int ni = 0; ni < 4; ++ni)
          acc[mi][ni] = __builtin_amdgcn_mfma_i32_16x16x64_i8(af[mi], bf[ni], acc[mi][ni], 0, 0, 0);
      __builtin_amdgcn_s_setprio(0);
    }
    asm volatile("s_waitcnt vmcnt(0)" ::: "memory");
    __builtin_amdgcn_s_barrier();
    __builtin_amdgcn_sched_barrier(0);
    buf ^= 1;
  }
#undef OSTAGE

  float w3 = wsc[3];
#pragma unroll
  for (int mi = 0; mi < 2; ++mi) {
#pragma unroll
    for (int rr = 0; rr < 4; ++rr) {
      int crow = bm + wave * 32 + mi * 16 + 4 * g + rr;
      float rs = asx[crow] * w3;
#pragma unroll
      for (int ni = 0; ni < 4; ++ni) {
        int ccol = bn + ni * 16 + l15;
        d0[(size_t)crow * 2048 + ccol] = (float)acc[mi][ni][rr] * rs;
      }
    }
  }
}

// ---------------------------------------------------------------------------
// K5: per-row act_quant for requant of attn out
// ---------------------------------------------------------------------------
__global__ __launch_bounds__(256) void k_actquant(const float* __restrict__ x,
                                                  signed char* __restrict__ xq,
                                                  float* __restrict__ as_inv) {
  int row = blockIdx.x, tid = threadIdx.x;
  int wave = tid >> 6, lane = tid & 63;
  const float4* xr4 = (const float4*)(x + (size_t)row * HH);
  float4 a = xr4[tid * 2], b = xr4[tid * 2 + 1];
  float am = fmaxf(fmaxf(fmaxf(fabsf(a.x), fabsf(a.y)), fmaxf(fabsf(a.z), fabsf(a.w))),
                   fmaxf(fmaxf(fabsf(b.x), fabsf(b.y)), fmaxf(fabsf(b.z), fabsf(b.w))));
#pragma unroll
  for (int o = 32; o; o >>= 1) am = fmaxf(am, __shfl_xor(am, o));
  __shared__ float wred[4];
  if (lane == 0) wred[wave] = am;
  __syncthreads();
  am = fmaxf(fmaxf(wred[0], wred[1]), fmaxf(wred[2], wred[3]));
  am = fmaxf(am, 1e-5f);
  if (tid == 0) as_inv[row] = am / 127.f;
  float scale = 127.f / am;
  float vals[8] = {a.x, a.y, a.z, a.w, b.x, b.y, b.z, b.w};
  unsigned int u0 = 0, u1 = 0;
#pragma unroll
  for (int j = 0; j < 4; ++j) {
    int q = (int)fminf(fmaxf(rintf(vals[j] * scale), -128.f), 127.f);
    u0 |= (unsigned int)(q & 255) << (8 * j);
  }
#pragma unroll
  for (int j = 0; j < 4; ++j) {
    int q = (int)fminf(fmaxf(rintf(vals[4 + j] * scale), -128.f), 127.f);
    u1 |= (unsigned int)(q & 255) << (8 * j);
  }
  uint2 uu; uu.x = u0; uu.y = u1;
  ((uint2*)(xq + (size_t)row * HH))[tid] = uu;
}

// ---------------------------------------------------------------------------
// K6: MFMA flash attention, 32 queries per wave (K/V LDS reads serve 2 q
// sub-tiles -> per-q LDS traffic halved). Block = 4 waves = 128 q = heavy
// q-tile (waves 0-1, qt_h) + light q-tile (waves 2-3, qt_l = 15-qt_h)
// sharing one staged KV stream over the heavy range; every block has
// exactly 34 active tile-waves (perfect balance). 256 blocks (1/CU),
// KV tile 64, 2-buffer stage-at-top pipeline. Blocks 256..383: wot quant
// (no LDS; co-resident with attn blocks).
// ---------------------------------------------------------------------------
__global__ __launch_bounds__(256) void k_attn_mfma(const unsigned short* __restrict__ qfp,
                                                   const unsigned short* __restrict__ kfp,
                                                   const unsigned short* __restrict__ vfp,
                                                   float* __restrict__ o,
                                                   const float* __restrict__ wsc,
                                                   const float* __restrict__ wo_f32,
                                                   signed char* __restrict__ wot) {
  int tid = threadIdx.x;
  if (blockIdx.x >= 256) {
    int bx = blockIdx.x - 256;          // 0..127
    float inv = 1.f / wsc[3];
    for (int qi = bx * 256 + tid; qi < 1048576; qi += 128 * 256) {
      float4 v = ((const float4*)wo_f32)[qi];
      unsigned int u = 0;
      float vv[4] = {v.x, v.y, v.z, v.w};
#pragma unroll
      for (int j = 0; j < 4; ++j) {
        int q = (int)fminf(fmaxf(rintf(vv[j] * inv), -1.f), 1.f);
        u |= (unsigned int)(q & 255) << (8 * j);
      }
      ((unsigned int*)wot)[qi] = u;
    }
    return;
  }

  int chunk = blockIdx.x & 7, j = blockIdx.x >> 3;   // XCD, within-chunk (0..31)
  int qpair = j >> 2;                                // 0..7
  int yy = (chunk << 2) + (j & 3);                   // bh, 4 heads/chunk share L2
  int b = yy >> 4, h = yy & 15, kvh = h >> 1;
  int qt_h = 15 - qpair, qt_l = qpair;
  int wave = tid >> 6, lane = tid & 63;
  int l15 = lane & 15, g = lane >> 4;
  int qt_w = (wave < 2) ? qt_h : qt_l;
  int q0w = qt_w * 64 + (wave & 1) * 32;             // 32 q per wave
  int qg0 = q0w + l15;                               // sub0 query
  int qg1 = q0w + 16 + l15;                          // sub1 query

  __shared__ unsigned short Kf[2][8192];     // fp16 K, [ki(64)][d(128)] swizzled
  __shared__ unsigned short Vf[2][8192];     // fp16 V^T [d(128)][tok(64)] swizzled
  __shared__ unsigned short Plds[4][2][16][68]; // fp16 P per wave per sub

  half8 qf0[4], qf1[4];
  {
    const unsigned short* qb0 = qfp + ((size_t)(b * SEQ + qg0) * NHQ + h) * HDD + g * 8;
    const unsigned short* qb1 = qfp + ((size_t)(b * SEQ + qg1) * NHQ + h) * HDD + g * 8;
#pragma unroll
    for (int c = 0; c < 4; ++c) {
      qf0[c] = s2h(*(const short8*)(qb0 + c * 32));
      qf1[c] = s2h(*(const short8*)(qb1 + c * 32));
    }
  }
  half8 vones;
#pragma unroll
  for (int c = 0; c < 8; ++c) vones[c] = (_Float16)1.0f;

#define STAGE64(KV0N, BUF)                                                            \
  {                                                                                   \
    _Pragma("unroll")                                                                 \
    for (int tch = 0; tch < 4; ++tch) {                                               \
      int c = tch * 256 + tid;                                                        \
      int ki = c >> 4, jb = (c & 15) << 4;                                            \
      int js = jb ^ ((ki & 7) << 4);                                                  \
      size_t kbase = ((size_t)(b * SEQ + (KV0N) + ki) * NKVH + kvh) * HDD;            \
      GLD_LDS16((const char*)(kfp + kbase) + js, &Kf[BUF][c * 8]);                    \
      int d = c >> 3, jv = (c & 7) << 4;                                              \
      int jvs = jv ^ ((d & 7) << 4);                                                  \
      size_t vbase = ((size_t)(b * 1024 + kvh * 128 + d)) * SEQ + (KV0N);             \
      GLD_LDS16((const char*)(vfp + vbase) + jvs, &Vf[BUF][c * 8]);                   \
    }                                                                                 \
  }

  f32x4 accA[9] = {}, accB[9] = {};   // sub0 / sub1: [0..7]=O d-tiles, [8]=l
  float m0 = -INFINITY, m1 = -INFINITY;
  int nkv = qt_h + 1;                 // heavy range covers both tiles

  STAGE64(0, 0);
  asm volatile("s_waitcnt vmcnt(0) lgkmcnt(0)" ::: "memory");
  __builtin_amdgcn_s_barrier();
  __builtin_amdgcn_sched_barrier(0);

  int buf = 0;
  for (int kv = 0; kv < nkv; ++kv) {
    int kv0 = kv * 64;
    bool more = (kv + 1 < nkv);
    if (more) STAGE64(kv0 + 64, buf ^ 1);   // issued early; compute covers latency
    bool active = (kv0 <= q0w + 31);
    if (active) {
      const char* Kb = (const char*)&Kf[buf][0];
      const char* Vb = (const char*)&Vf[buf][0];
      // ---- QK^T for both q sub-tiles; each K fragment read once ----
      float s0[4][4], s1[4][4];
      __builtin_amdgcn_s_setprio(1);
#pragma unroll
      for (int t = 0; t < 4; ++t) {
        int row = 16 * t + l15;
        int rbyte = row * 256, sw = (row & 7) << 4;
        f32x4 a0 = {0.f, 0.f, 0.f, 0.f};
        f32x4 a1 = {0.f, 0.f, 0.f, 0.f};
#pragma unroll
        for (int c = 0; c < 4; ++c) {
          int off = rbyte + ((c * 64 + g * 16) ^ sw);
          half8 kf8 = s2h(*(const short8*)(Kb + off));
          a0 = __builtin_amdgcn_mfma_f32_16x16x32_f16(kf8, qf0[c], a0, 0, 0, 0);
          a1 = __builtin_amdgcn_mfma_f32_16x16x32_f16(kf8, qf1[c], a1, 0, 0, 0);
        }
#pragma unroll
        for (int r = 0; r < 4; ++r) { s0[t][r] = a0[r]; s1[t][r] = a1[r]; }
      }
      __builtin_amdgcn_s_setprio(0);
      // ---- causal mask ----
      if (kv0 + 63 > q0w) {
#pragma unroll
        for (int t = 0; t < 4; ++t)
#pragma unroll
          for (int r = 0; r < 4; ++r) {
            int key = kv0 + 16 * t + 4 * g + r;
            if (key > qg0) s0[t][r] = -INFINITY;
            if (key > qg1) s1[t][r] = -INFINITY;
          }
      }
      // ---- online softmax (exp2; defer-max, per-lane check), both subs ----
      float p0 = -INFINITY, p1 = -INFINITY;
#pragma unroll
      for (int t = 0; t < 4; ++t)
#pragma unroll
        for (int r = 0; r < 4; ++r) {
          p0 = fmaxf(p0, s0[t][r]);
          p1 = fmaxf(p1, s1[t][r]);
        }
      if (!__all(p0 <= m0 + 10.f && p1 <= m1 + 10.f)) {
        p0 = fmaxf(p0, __shfl_xor(p0, 16)); p0 = fmaxf(p0, __shfl_xor(p0, 32));
        p1 = fmaxf(p1, __shfl_xor(p1, 16)); p1 = fmaxf(p1, __shfl_xor(p1, 32));
        float mn0 = fmaxf(m0, p0), mn1 = fmaxf(m1, p1);
        float c0 = exp2f(m0 - mn0), c1 = exp2f(m1 - mn1);
        m0 = mn0; m1 = mn1;
        float co0[4], co1[4];
#pragma unroll
        for (int r = 0; r < 4; ++r) {
          co0[r] = __shfl(c0, 4 * g + r);
          co1[r] = __shfl(c1, 4 * g + r);
        }
#pragma unroll
        for (int dt = 0; dt < 9; ++dt)
#pragma unroll
          for (int r = 0; r < 4; ++r) {
            accA[dt][r] *= co0[r];
            accB[dt][r] *= co1[r];
          }
      }
      // ---- P -> fp16, transpose through per-wave per-sub LDS ----
      ushort4 wh;
#pragma unroll
      for (int t = 0; t < 4; ++t) {
        wh.x = f2h(exp2f(s0[t][0] - m0));
        wh.y = f2h(exp2f(s0[t][1] - m0));
        wh.z = f2h(exp2f(s0[t][2] - m0));
        wh.w = f2h(exp2f(s0[t][3] - m0));
        *(ushort4*)&Plds[wave][0][l15][16 * t + 4 * g] = wh;
        wh.x = f2h(exp2f(s1[t][0] - m1));
        wh.y = f2h(exp2f(s1[t][1] - m1));
        wh.z = f2h(exp2f(s1[t][2] - m1));
        wh.w = f2h(exp2f(s1[t][3] - m1));
        *(ushort4*)&Plds[wave][1][l15][16 * t + 4 * g] = wh;
      }
      half8 pa0s0 = s2h(*(const short8*)&Plds[wave][0][l15][8 * g]);
      half8 pa1s0 = s2h(*(const short8*)&Plds[wave][0][l15][32 + 8 * g]);
      half8 pa0s1 = s2h(*(const short8*)&Plds[wave][1][l15][8 * g]);
      half8 pa1s1 = s2h(*(const short8*)&Plds[wave][1][l15][32 + 8 * g]);
      // ---- PV: each V fragment read once, feeds both subs ----
      __builtin_amdgcn_s_setprio(1);
#pragma unroll
      for (int dt = 0; dt < 8; ++dt) {
        int d = dt * 16 + l15;
        int rbase = d * 128, sw = (d & 7) << 4;
        half8 v0 = s2h(*(const short8*)(Vb + rbase + ((g * 16) ^ sw)));
        half8 v1 = s2h(*(const short8*)(Vb + rbase + ((64 + g * 16) ^ sw)));
        accA[dt] = __builtin_amdgcn_mfma_f32_16x16x32_f16(pa0s0, v0, accA[dt], 0, 0, 0);
        accA[dt] = __builtin_amdgcn_mfma_f32_16x16x32_f16(pa1s0, v1, accA[dt], 0, 0, 0);
        accB[dt] = __builtin_amdgcn_mfma_f32_16x16x32_f16(pa0s1, v0, accB[dt], 0, 0, 0);
        accB[dt] = __builtin_amdgcn_mfma_f32_16x16x32_f16(pa1s1, v1, accB[dt], 0, 0, 0);
      }
      accA[8] = __builtin_amdgcn_mfma_f32_16x16x32_f16(pa0s0, vones, accA[8], 0, 0, 0);
      accA[8] = __builtin_amdgcn_mfma_f32_16x16x32_f16(pa1s0, vones, accA[8], 0, 0, 0);
      accB[8] = __builtin_amdgcn_mfma_f32_16x16x32_f16(pa0s1, vones, accB[8], 0, 0, 0);
      accB[8] = __builtin_amdgcn_mfma_f32_16x16x32_f16(pa1s1, vones, accB[8], 0, 0, 0);
      __builtin_amdgcn_s_setprio(0);
    }
    asm volatile("s_waitcnt vmcnt(0)" ::: "memory");   // next buf landed (covered)
    __builtin_amdgcn_s_barrier();
    __builtin_amdgcn_sched_barrier(0);
    buf ^= 1;
  }
#undef STAGE64

  // ---- finalize both subs ----
  float lA[4], lB[4];
#pragma unroll
  for (int r = 0; r < 4; ++r) {
    lA[r] = 1.f / accA[8][r];
    lB[r] = 1.f / accB[8][r];
  }
#pragma unroll
  for (int r = 0; r < 4; ++r) {
    size_t orA = ((size_t)(b * SEQ + q0w + 4 * g + r) * NHQ + h) * HDD + l15;
    size_t orB = ((size_t)(b * SEQ + q0w + 16 + 4 * g + r) * NHQ + h) * HDD + l15;
#pragma unroll
    for (int dt = 0; dt < 8; ++dt) {
      o[orA + dt * 16] = accA[dt][r] * lA[r];
      o[orB + dt * 16] = accB[dt][r] * lB[r];
    }
  }
}

// ---------------------------------------------------------------------------
extern "C" void kernel_launch(void* const* d_in, const int* in_sizes, int n_in,
                              void* d_out, int out_size, void* d_ws, size_t ws_size,
                              hipStream_t stream) {
  const float* x  = (const float*)d_in[0];
  const float* cs = (const float*)d_in[1];
  const float* sn = (const float*)d_in[2];
  const float* wq = (const float*)d_in[3];
  const float* wk = (const float*)d_in[4];
  const float* wv = (const float*)d_in[5];
  const float* wo = (const float*)d_in[6];
  const float* qn = (const float*)d_in[7];
  const float* kn = (const float*)d_in[8];
  float* out = (float*)d_out;
  char* ws = (char*)d_ws;

  const size_t MB = 1024 * 1024;
  size_t o_xq  = 0;            // 4 MB  int8 xq
  size_t o_wqk = 4  * MB;      // 6 MB  [3072][2048] i8
  size_t o_wvt = 10 * MB;      // 2 MB  [1024][2048] i8
  size_t o_wot = 12 * MB;      // 4 MB  [2048][2048] i8
  size_t o_vt  = 16 * MB;      // 4 MB  fp16 V transposed
  size_t o_qf  = 20 * MB;      // 8 MB  fp16 q (rope'd, log2e/sqrt(128) folded)
  size_t o_kf  = 28 * MB;      // 4 MB  fp16 k (rope'd)
  size_t o_ao  = 32 * MB;      // 16 MB f32 attn out
  size_t o_aq  = 48 * MB;      // 4 MB  int8 requant
  size_t o_as  = 52 * MB;
  size_t o_as2 = o_as  + 8192;
  size_t o_prt = o_as2 + 8192;
  size_t o_wsc = o_prt + 8192;

  signed char* xq  = (signed char*)(ws + o_xq);
  signed char* wqk = (signed char*)(ws + o_wqk);
  signed char* wvt = (signed char*)(ws + o_wvt);
  signed char* wot = (signed char*)(ws + o_wot);
  unsigned short* vt = (unsigned short*)(ws + o_vt);
  unsigned short* qf = (unsigned short*)(ws + o_qf);
  unsigned short* kf = (unsigned short*)(ws + o_kf);
  float* ao = (float*)(ws + o_ao);
  signed char* aq = (signed char*)(ws + o_aq);
  float* asx = (float*)(ws + o_as);
  float* as2 = (float*)(ws + o_as2);
  double* prt = (double*)(ws + o_prt);
  float* wsc = (float*)(ws + o_wsc);

  // 1) act quant of x + weight |w| partials (one dispatch)
  k_quant_stats<<<3072, 256, 0, stream>>>(x, xq, asx, wq, wk, wv, wo, prt);

  // 2) ternary quant of wq/wk/wv (publishes wsc)
  k_wquant_all<<<1024, 256, 0, stream>>>(wq, wk, wv, wqk, wvt, prt, wsc);

  // 3) fused QKV projection + rmsnorm/rope epilogue (128x128, BK=128)
  k_gemm_i8<<<512, 256, 0, stream>>>(xq, wqk, wvt, vt, asx, wsc,
                                     qn, kn, cs, sn, qf, kf);

  // 4) MFMA flash attention (32 q/wave, heavy+light pair per block)
  //    + co-resident wot quant
  k_attn_mfma<<<384, 256, 0, stream>>>(qf, kf, vt, ao, wsc, wo, wot);

  // 5) re-quant + output projection (128x64, BK=128, 512 blocks)
  k_actquant<<<TT, 256, 0, stream>>>(ao, aq, as2);
  k_gemm_o<<<512, 256, 0, stream>>>(aq, wot, out, as2, wsc);
}

// Round 17
// 117.252 us; speedup vs baseline: 1.0159x; 1.0159x over previous
//
#include <hip/hip_runtime.h>
#include <hip/hip_bf16.h>

#define TT   2048   // B*S tokens
#define HH   2048   // hidden dim
#define SEQ  1024
#define NHQ  16
#define NKVH 8
#define HDD  128

typedef __attribute__((ext_vector_type(8))) short short8;
typedef __attribute__((ext_vector_type(4))) float f32x4;
typedef __attribute__((ext_vector_type(4))) int int4v;
typedef _Float16 half8 __attribute__((ext_vector_type(8)));

static __device__ __forceinline__ unsigned short f2h(float f) {
  union { _Float16 h; unsigned short u; } c;
  c.h = (_Float16)f;
  return c.u;
}
static __device__ __forceinline__ half8 s2h(short8 v) {
  union { short8 s; half8 h; } c;
  c.s = v;
  return c.h;
}

#define GLD_LDS16(gp, lp)                                                        \
  __builtin_amdgcn_global_load_lds(                                              \
      (const __attribute__((address_space(1))) void*)(const void*)(gp),          \
      (__attribute__((address_space(3))) void*)(void*)(lp), 16, 0, 0)

// ---------------------------------------------------------------------------
// K1: fused act_quant(x) + weight |w| partial sums, one dispatch.
// ---------------------------------------------------------------------------
__global__ __launch_bounds__(256) void k_quant_stats(const float* __restrict__ x,
                                                     signed char* __restrict__ xq,
                                                     float* __restrict__ as_inv,
                                                     const float* __restrict__ wq,
                                                     const float* __restrict__ wk,
                                                     const float* __restrict__ wv,
                                                     const float* __restrict__ wo,
                                                     double* __restrict__ part) {
  int tid = threadIdx.x;
  int wave = tid >> 6, lane = tid & 63;
  __shared__ double redd[256];
  __shared__ float wred[4];

  if (blockIdx.x < 2048) {
    int row = blockIdx.x;
    const float4* xr4 = (const float4*)(x + (size_t)row * HH);
    float4 a = xr4[tid * 2], b = xr4[tid * 2 + 1];
    float am = fmaxf(fmaxf(fmaxf(fabsf(a.x), fabsf(a.y)), fmaxf(fabsf(a.z), fabsf(a.w))),
                     fmaxf(fmaxf(fabsf(b.x), fabsf(b.y)), fmaxf(fabsf(b.z), fabsf(b.w))));
#pragma unroll
    for (int o = 32; o; o >>= 1) am = fmaxf(am, __shfl_xor(am, o));
    if (lane == 0) wred[wave] = am;
    __syncthreads();
    am = fmaxf(fmaxf(wred[0], wred[1]), fmaxf(wred[2], wred[3]));
    am = fmaxf(am, 1e-5f);
    if (tid == 0) as_inv[row] = am / 127.f;
    float scale = 127.f / am;
    float vals[8] = {a.x, a.y, a.z, a.w, b.x, b.y, b.z, b.w};
    unsigned int u0 = 0, u1 = 0;
#pragma unroll
    for (int j = 0; j < 4; ++j) {
      int q = (int)fminf(fmaxf(rintf(vals[j] * scale), -128.f), 127.f);
      u0 |= (unsigned int)(q & 255) << (8 * j);
    }
#pragma unroll
    for (int j = 0; j < 4; ++j) {
      int q = (int)fminf(fmaxf(rintf(vals[4 + j] * scale), -128.f), 127.f);
      u1 |= (unsigned int)(q & 255) << (8 * j);
    }
    uint2 uu; uu.x = u0; uu.y = u1;
    ((uint2*)(xq + (size_t)row * HH))[tid] = uu;
  } else {
    int idx = blockIdx.x - 2048;
    int wid = idx >> 8, sub = idx & 255;
    const float* w = (wid == 0) ? wq : (wid == 1) ? wk : (wid == 2) ? wv : wo;
    int nq = ((wid == 0 || wid == 3) ? 4194304 : 2097152) >> 2;
    double s = 0.0;
    for (int i = sub * 256 + tid; i < nq; i += 256 * 256) {
      float4 v = ((const float4*)w)[i];
      s += (double)fabsf(v.x) + (double)fabsf(v.y) + (double)fabsf(v.z) + (double)fabsf(v.w);
    }
    redd[tid] = s;
    __syncthreads();
    for (int st = 128; st > 0; st >>= 1) {
      if (tid < st) redd[tid] += redd[tid + st];
      __syncthreads();
    }
    if (tid == 0) part[wid * 256 + sub] = redd[0];
  }
}

// ---------------------------------------------------------------------------
// K3: ternary weight quant -> int8 for wq,wk,wv. Block 0 publishes wsc.
// ---------------------------------------------------------------------------
__global__ __launch_bounds__(256) void k_wquant_all(const float* __restrict__ wq,
                                                    const float* __restrict__ wk,
                                                    const float* __restrict__ wv,
                                                    signed char* __restrict__ wqk,
                                                    signed char* __restrict__ wvt,
                                                    const double* __restrict__ part,
                                                    float* __restrict__ wsc) {
  int tid = threadIdx.x;
  int wave = tid >> 6, lane = tid & 63;
  __shared__ double wred[4][4];
  __shared__ float s_wsc[4];
  const double nvals[4] = {4194304.0, 2097152.0, 2097152.0, 4194304.0};
#pragma unroll
  for (int w = 0; w < 4; ++w) {
    double s = part[w * 256 + tid];
#pragma unroll
    for (int o = 32; o; o >>= 1) s += __shfl_xor(s, o);
    if (lane == 0) wred[w][wave] = s;
  }
  __syncthreads();
  if (tid < 4) {
    double s = (wred[tid][0] + wred[tid][1]) + (wred[tid][2] + wred[tid][3]);
    float v = fmaxf((float)(s / nvals[tid]), 1e-5f);
    s_wsc[tid] = v;
    if (blockIdx.x == 0) wsc[tid] = v;
  }
  __syncthreads();
  float inv0 = 1.f / s_wsc[0], inv1 = 1.f / s_wsc[1], inv2 = 1.f / s_wsc[2];

  const int NQ = 2097152;   // wq(1048576) + wk(524288) + wv(524288) quads
  for (int qi = blockIdx.x * 256 + tid; qi < NQ; qi += gridDim.x * 256) {
    const float* src; signed char* dst; float inv; int off;
    if (qi < 1048576)      { src = wq; dst = wqk;           off = qi;           inv = inv0; }
    else if (qi < 1572864) { src = wk; dst = wqk + 4194304; off = qi - 1048576; inv = inv1; }
    else                   { src = wv; dst = wvt;           off = qi - 1572864; inv = inv2; }
    float4 v = ((const float4*)src)[off];
    unsigned int u = 0;
    float vv[4] = {v.x, v.y, v.z, v.w};
#pragma unroll
    for (int j = 0; j < 4; ++j) {
      int q = (int)fminf(fmaxf(rintf(vv[j] * inv), -1.f), 1.f);
      u |= (unsigned int)(q & 255) << (8 * j);
    }
    ((unsigned int*)dst)[off] = u;
  }
}

// ---------------------------------------------------------------------------
// K4: QKV i8 MFMA NT-GEMM, 128x128 tile, BK=128, 2-buffer stage-at-top
// pipeline, 8-way XOR swizzle, 512 blocks. (round-13 configuration)
// ---------------------------------------------------------------------------
__global__ __launch_bounds__(256) void k_gemm_i8(const signed char* __restrict__ A0,
                                                 const signed char* __restrict__ B0,
                                                 const signed char* __restrict__ B1,
                                                 unsigned short* __restrict__ dh,
                                                 const float* __restrict__ asx,
                                                 const float* __restrict__ wsc,
                                                 const float* __restrict__ qn,
                                                 const float* __restrict__ kn,
                                                 const float* __restrict__ cs,
                                                 const float* __restrict__ sn,
                                                 unsigned short* __restrict__ qf,
                                                 unsigned short* __restrict__ kf) {
  const int K = HH;
  __shared__ signed char As[2][16384];   // [buf][128][128] swizzled rows
  __shared__ signed char Bs[2][16384];
  int tid = threadIdx.x;
  int wave = tid >> 6, lane = tid & 63, l15 = lane & 15, g = lane >> 4;
  int wm = wave >> 1, wn = wave & 1;

  int gid = (blockIdx.x & 7) * 64 + (blockIdx.x >> 3);   // XCD chunk, 512 blocks
  const signed char *Ap, *Bp;
  int bm, bn, mode;
  if (gid < 384) { mode = 0; bm = (gid / 24) * 128; bn = (gid % 24) * 128; Ap = A0; Bp = B0; }
  else { mode = 1; int vid = gid - 384; bm = (vid >> 4) * 128; bn = (vid & 15) * 128; Ap = B1; Bp = A0; }

#define GSTAGE(K0, BUF)                                                               \
  {                                                                                   \
    _Pragma("unroll")                                                                 \
    for (int r = 0; r < 4; ++r) {                                                     \
      int c = r * 256 + tid;                                                          \
      int row = c >> 3;                                                               \
      int kk2 = ((c & 7) << 4) ^ ((row & 7) << 4);                                    \
      GLD_LDS16(Ap + (size_t)(bm + row) * K + (K0) + kk2, As[BUF] + c * 16);          \
      GLD_LDS16(Bp + (size_t)(bn + row) * K + (K0) + kk2, Bs[BUF] + c * 16);          \
    }                                                                                 \
  }

  int4v acc[4][4] = {};
  GSTAGE(0, 0);
  asm volatile("s_waitcnt vmcnt(0)" ::: "memory");
  __builtin_amdgcn_s_barrier();
  __builtin_amdgcn_sched_barrier(0);

  int buf = 0;
  for (int k0 = 0; k0 < K; k0 += 128) {
    bool more = (k0 + 128 < K);
    if (more) GSTAGE(k0 + 128, buf ^ 1);   // issued early; compute covers latency
#pragma unroll
    for (int ks = 0; ks < 2; ++ks) {
      int4v af[4], bf[4];
#pragma unroll
      for (int i = 0; i < 4; ++i) {
        int ra = wm * 64 + i * 16 + l15;
        af[i] = *(const int4v*)&As[buf][ra * 128 + ((ks * 64 + g * 16) ^ ((ra & 7) << 4))];
        int rb = (mode == 0) ? (wn * 32 + (i & 1) * 16 + (i >> 1) * 64 + l15)
                             : (wn * 64 + i * 16 + l15);
        bf[i] = *(const int4v*)&Bs[buf][rb * 128 + ((ks * 64 + g * 16) ^ ((rb & 7) << 4))];
      }
      __builtin_amdgcn_s_setprio(1);
#pragma unroll
      for (int mi = 0; mi < 4; ++mi)
#pragma unroll
        for (int ni = 0; ni < 4; ++ni)
          acc[mi][ni] = __builtin_amdgcn_mfma_i32_16x16x64_i8(af[mi], bf[ni], acc[mi][ni], 0, 0, 0);
      __builtin_amdgcn_s_setprio(0);
    }
    asm volatile("s_waitcnt vmcnt(0)" ::: "memory");
    __builtin_amdgcn_s_barrier();
    __builtin_amdgcn_sched_barrier(0);
    buf ^= 1;
  }
#undef GSTAGE

  if (mode == 0) {
    // fused rmsnorm + rope epilogue -> single fp16
    bool isq = (bn < 2048);
    int hh = isq ? (bn >> 7) : ((bn - 2048) >> 7);
    float wN = isq ? wsc[0] : wsc[1];
    float ps = isq ? 0.12751743075f : 1.0f;   // (1/sqrt(128))*log2(e) for q
    const float* nw = isq ? qn : kn;
    unsigned short* oh = isq ? qf : kf;
    int nhp = isq ? NHQ : NKVH;
    float* S = (float*)&As[0][0];        // reuse LDS: [2][128] f32
    __syncthreads();
#pragma unroll
    for (int mi = 0; mi < 4; ++mi) {
#pragma unroll
      for (int rr = 0; rr < 4; ++rr) {
        int tok = bm + wm * 64 + mi * 16 + 4 * g + rr;
        float rs = asx[tok] * wN;
        float ssum = 0.f;
#pragma unroll
        for (int ni = 0; ni < 4; ++ni) {
          float v = (float)acc[mi][ni][rr] * rs;
          ssum += v * v;
        }
        ssum += __shfl_xor(ssum, 1); ssum += __shfl_xor(ssum, 2);
        ssum += __shfl_xor(ssum, 4); ssum += __shfl_xor(ssum, 8);
        if (l15 == 0) S[wn * 128 + wm * 64 + mi * 16 + 4 * g + rr] = ssum;
      }
    }
    __syncthreads();
#pragma unroll
    for (int mi = 0; mi < 4; ++mi) {
#pragma unroll
      for (int rr = 0; rr < 4; ++rr) {
        int rloc = wm * 64 + mi * 16 + 4 * g + rr;
        int tok = bm + rloc;
        float rs = asx[tok] * wN;
        float inv = rsqrtf((S[rloc] + S[128 + rloc]) * (1.f / 128.f) + 1e-6f);
        int s = tok & (SEQ - 1);
        float nv[4];
#pragma unroll
        for (int ni = 0; ni < 4; ++ni) {
          int d = wn * 32 + (ni & 1) * 16 + (ni >> 1) * 64 + l15;
          nv[ni] = nw[d] * ((float)acc[mi][ni][rr] * rs) * inv;
        }
#pragma unroll
        for (int ni = 0; ni < 4; ++ni) {
          int d = wn * 32 + (ni & 1) * 16 + (ni >> 1) * 64 + l15;
          float oo = nv[ni ^ 2];
          float rh = (ni < 2) ? -oo : oo;
          float res = (nv[ni] * cs[s * 128 + d] + rh * sn[s * 128 + d]) * ps;
          size_t oi = ((size_t)tok * nhp + hh) * 128 + d;
          oh[oi] = f2h(res);
        }
      }
    }
  } else {   // mode 1: V fp16 transposed (crow=feature, ccol=token)
    float w2 = wsc[2];
#pragma unroll
    for (int mi = 0; mi < 4; ++mi) {
#pragma unroll
      for (int rr = 0; rr < 4; ++rr) {
        int crow = bm + wm * 64 + mi * 16 + 4 * g + rr;
#pragma unroll
        for (int ni = 0; ni < 4; ++ni) {
          int ccol = bn + wn * 64 + ni * 16 + l15;
          float v = (float)acc[mi][ni][rr] * asx[ccol] * w2;
          size_t ad = ((size_t)((ccol >> 10) * 1024 + crow)) * 1024 + (ccol & 1023);
          dh[ad] = f2h(v);
        }
      }
    }
  }
}

// ---------------------------------------------------------------------------
// K4b: O projection, 128x64 tiles, BK=128, 512 blocks, 2-buffer pipeline.
// (round-14 configuration)
// ---------------------------------------------------------------------------
__global__ __launch_bounds__(256) void k_gemm_o(const signed char* __restrict__ A,
                                                const signed char* __restrict__ B,
                                                float* __restrict__ d0,
                                                const float* __restrict__ asx,
                                                const float* __restrict__ wsc) {
  const int K = HH;
  __shared__ signed char As[2][16384];   // [buf][128][128]
  __shared__ signed char Bs[2][8192];    // [buf][64][128]
  int tid = threadIdx.x;
  int wave = tid >> 6, lane = tid & 63, l15 = lane & 15, g = lane >> 4;
  int gid = (blockIdx.x & 7) * 64 + (blockIdx.x >> 3);
  int bm = (gid >> 5) * 128, bn = (gid & 31) * 64;

#define OSTAGE(K0, BUF)                                                               \
  {                                                                                   \
    _Pragma("unroll")                                                                 \
    for (int r = 0; r < 4; ++r) {                                                     \
      int c = r * 256 + tid;                                                          \
      int row = c >> 3;                                                               \
      int kk2 = ((c & 7) << 4) ^ ((row & 7) << 4);                                    \
      GLD_LDS16(A + (size_t)(bm + row) * K + (K0) + kk2, As[BUF] + c * 16);           \
    }                                                                                 \
    _Pragma("unroll")                                                                 \
    for (int r = 0; r < 2; ++r) {                                                     \
      int c = r * 256 + tid;                                                          \
      int row = c >> 3;                                                               \
      int kk2 = ((c & 7) << 4) ^ ((row & 7) << 4);                                    \
      GLD_LDS16(B + (size_t)(bn + row) * K + (K0) + kk2, Bs[BUF] + c * 16);           \
    }                                                                                 \
  }

  int4v acc[2][4] = {};
  OSTAGE(0, 0);
  asm volatile("s_waitcnt vmcnt(0)" ::: "memory");
  __builtin_amdgcn_s_barrier();
  __builtin_amdgcn_sched_barrier(0);

  int buf = 0;
  for (int k0 = 0; k0 < K; k0 += 128) {
    bool more = (k0 + 128 < K);
    if (more) OSTAGE(k0 + 128, buf ^ 1);
#pragma unroll
    for (int ks = 0; ks < 2; ++ks) {
      int4v af[2], bf[4];
#pragma unroll
      for (int i = 0; i < 2; ++i) {
        int ra = wave * 32 + i * 16 + l15;
        af[i] = *(const int4v*)&As[buf][ra * 128 + ((ks * 64 + g * 16) ^ ((ra & 7) << 4))];
      }
#pragma unroll
      for (int n = 0; n < 4; ++n) {
        int rb = n * 16 + l15;
        bf[n] = *(const int4v*)&Bs[buf][rb * 128 + ((ks * 64 + g * 16) ^ ((rb & 7) << 4))];
      }
      __builtin_amdgcn_s_setprio(1);
#pragma unroll
      for (int mi = 0; mi < 2; ++mi)
#pragma unroll
        for (int ni = 0; ni < 4; ++ni)
          acc[mi][ni] = __builtin_amdgcn_mfma_i32_16x16x64_i8(af[mi], bf[ni], acc[mi][ni], 0, 0, 0);
      __builtin_amdgcn_s_setprio(0);
    }
    asm volatile("s_waitcnt vmcnt(0)" ::: "memory");
    __builtin_amdgcn_s_barrier();
    __builtin_amdgcn_sched_barrier(0);
    buf ^= 1;
  }
#undef OSTAGE

  float w3 = wsc[3];
#pragma unroll
  for (int mi = 0; mi < 2; ++mi) {
#pragma unroll
    for (int rr = 0; rr < 4; ++rr) {
      int crow = bm + wave * 32 + mi * 16 + 4 * g + rr;
      float rs = asx[crow] * w3;
#pragma unroll
      for (int ni = 0; ni < 4; ++ni) {
        int ccol = bn + ni * 16 + l15;
        d0[(size_t)crow * 2048 + ccol] = (float)acc[mi][ni][rr] * rs;
      }
    }
  }
}

// ---------------------------------------------------------------------------
// K5: per-row act_quant of attn out (blocks 0..2047) + wot ternary quant
// (blocks 2048..2175; no LDS footprint -> overlaps fully; completes before
// k_gemm_o by stream order).
// ---------------------------------------------------------------------------
__global__ __launch_bounds__(256) void k_actquant(const float* __restrict__ x,
                                                  signed char* __restrict__ xq,
                                                  float* __restrict__ as_inv,
                                                  const float* __restrict__ wsc,
                                                  const float* __restrict__ wo_f32,
                                                  signed char* __restrict__ wot) {
  int tid = threadIdx.x;
  if (blockIdx.x >= 2048) {
    int bx = blockIdx.x - 2048;         // 0..127
    float inv = 1.f / wsc[3];
    for (int qi = bx * 256 + tid; qi < 1048576; qi += 128 * 256) {
      float4 v = ((const float4*)wo_f32)[qi];
      unsigned int u = 0;
      float vv[4] = {v.x, v.y, v.z, v.w};
#pragma unroll
      for (int j = 0; j < 4; ++j) {
        int q = (int)fminf(fmaxf(rintf(vv[j] * inv), -1.f), 1.f);
        u |= (unsigned int)(q & 255) << (8 * j);
      }
      ((unsigned int*)wot)[qi] = u;
    }
    return;
  }
  int row = blockIdx.x;
  int wave = tid >> 6, lane = tid & 63;
  const float4* xr4 = (const float4*)(x + (size_t)row * HH);
  float4 a = xr4[tid * 2], b = xr4[tid * 2 + 1];
  float am = fmaxf(fmaxf(fmaxf(fabsf(a.x), fabsf(a.y)), fmaxf(fabsf(a.z), fabsf(a.w))),
                   fmaxf(fmaxf(fabsf(b.x), fabsf(b.y)), fmaxf(fabsf(b.z), fabsf(b.w))));
#pragma unroll
  for (int o = 32; o; o >>= 1) am = fmaxf(am, __shfl_xor(am, o));
  __shared__ float wred[4];
  if (lane == 0) wred[wave] = am;
  __syncthreads();
  am = fmaxf(fmaxf(wred[0], wred[1]), fmaxf(wred[2], wred[3]));
  am = fmaxf(am, 1e-5f);
  if (tid == 0) as_inv[row] = am / 127.f;
  float scale = 127.f / am;
  float vals[8] = {a.x, a.y, a.z, a.w, b.x, b.y, b.z, b.w};
  unsigned int u0 = 0, u1 = 0;
#pragma unroll
  for (int j = 0; j < 4; ++j) {
    int q = (int)fminf(fmaxf(rintf(vals[j] * scale), -128.f), 127.f);
    u0 |= (unsigned int)(q & 255) << (8 * j);
  }
#pragma unroll
  for (int j = 0; j < 4; ++j) {
    int q = (int)fminf(fmaxf(rintf(vals[4 + j] * scale), -128.f), 127.f);
    u1 |= (unsigned int)(q & 255) << (8 * j);
  }
  uint2 uu; uu.x = u0; uu.y = u1;
  ((uint2*)(xq + (size_t)row * HH))[tid] = uu;
}

// ---------------------------------------------------------------------------
// K6: MFMA flash attention, KV tile 64, 2-buffer stage-at-top pipeline,
// balanced CU pairing, 512 pure-attn blocks (round-14 configuration,
// wot quant removed).
// ---------------------------------------------------------------------------
__global__ __launch_bounds__(256) void k_attn_mfma(const unsigned short* __restrict__ qfp,
                                                   const unsigned short* __restrict__ kfp,
                                                   const unsigned short* __restrict__ vfp,
                                                   float* __restrict__ o) {
  int tid = threadIdx.x;
  int chunk = blockIdx.x & 7, j = blockIdx.x >> 3;   // XCD, within-chunk
  int qt, yyi;
  if (j < 32) { qt = 15 - (j >> 2); yyi = j & 3; }          // heavy half first
  else        { qt = (j - 32) >> 2; yyi = (j - 32) & 3; }   // paired light half
  int yy = (chunk << 2) + yyi;
  int b = yy >> 4, h = yy & 15, kvh = h >> 1;
  int wave = tid >> 6, lane = tid & 63;
  int l15 = lane & 15, g = lane >> 4;
  int q0w = qt * 64 + wave * 16;
  int qglob = q0w + l15;

  __shared__ unsigned short Kf[2][8192];     // fp16 K, [ki(64)][d(128)] swizzled
  __shared__ unsigned short Vf[2][8192];     // fp16 V^T [d(128)][tok(64)] swizzled
  __shared__ unsigned short Plds[4][16][72]; // fp16 P, 64 keys + pad

  half8 qf[4];
  {
    const unsigned short* qb = qfp + ((size_t)(b * SEQ + qglob) * NHQ + h) * HDD + g * 8;
#pragma unroll
    for (int c = 0; c < 4; ++c) qf[c] = s2h(*(const short8*)(qb + c * 32));
  }
  half8 vones;
#pragma unroll
  for (int c = 0; c < 8; ++c) vones[c] = (_Float16)1.0f;

#define STAGE64(KV0N, BUF)                                                            \
  {                                                                                   \
    _Pragma("unroll")                                                                 \
    for (int tch = 0; tch < 4; ++tch) {                                               \
      int c = tch * 256 + tid;                                                        \
      int ki = c >> 4, jb = (c & 15) << 4;                                            \
      int js = jb ^ ((ki & 7) << 4);                                                  \
      size_t kbase = ((size_t)(b * SEQ + (KV0N) + ki) * NKVH + kvh) * HDD;            \
      GLD_LDS16((const char*)(kfp + kbase) + js, &Kf[BUF][c * 8]);                    \
      int d = c >> 3, jv = (c & 7) << 4;                                              \
      int jvs = jv ^ ((d & 7) << 4);                                                  \
      size_t vbase = ((size_t)(b * 1024 + kvh * 128 + d)) * SEQ + (KV0N);             \
      GLD_LDS16((const char*)(vfp + vbase) + jvs, &Vf[BUF][c * 8]);                   \
    }                                                                                 \
  }

  f32x4 acc[9] = {};                 // [0..7]=O d-tiles, [8]=l (ones-V)
  float m_run = -INFINITY;
  int nkv = qt + 1;                  // 64-key tiles

  STAGE64(0, 0);
  asm volatile("s_waitcnt vmcnt(0) lgkmcnt(0)" ::: "memory");
  __builtin_amdgcn_s_barrier();
  __builtin_amdgcn_sched_barrier(0);

  int buf = 0;
  for (int kv = 0; kv < nkv; ++kv) {
    int kv0 = kv * 64;
    bool more = (kv + 1 < nkv);
    if (more) STAGE64(kv0 + 64, buf ^ 1);   // issued early; compute covers latency
    bool active = (kv0 <= q0w + 15);
    if (active) {
      const char* Kb = (const char*)&Kf[buf][0];
      const char* Vb = (const char*)&Vf[buf][0];
      // ---- QK^T (fp16, scores in log2 units): 4 tiles of 16 keys ----
      float sc[4][4];
      __builtin_amdgcn_s_setprio(1);
#pragma unroll
      for (int t = 0; t < 4; ++t) {
        int row = 16 * t + l15;
        int rbyte = row * 256, sw = (row & 7) << 4;
        f32x4 s = {0.f, 0.f, 0.f, 0.f};
#pragma unroll
        for (int c = 0; c < 4; ++c) {
          int off = rbyte + ((c * 64 + g * 16) ^ sw);
          half8 kf8 = s2h(*(const short8*)(Kb + off));
          s = __builtin_amdgcn_mfma_f32_16x16x32_f16(kf8, qf[c], s, 0, 0, 0);
        }
#pragma unroll
        for (int r = 0; r < 4; ++r) sc[t][r] = s[r];
      }
      __builtin_amdgcn_s_setprio(0);
      if (kv0 + 63 > q0w) {
#pragma unroll
        for (int t = 0; t < 4; ++t)
#pragma unroll
          for (int r = 0; r < 4; ++r)
            if (kv0 + 16 * t + 4 * g + r > qglob) sc[t][r] = -INFINITY;
      }
      // ---- online softmax (exp2; defer-max, per-lane check) ----
      float pmax = -INFINITY;
#pragma unroll
      for (int t = 0; t < 4; ++t)
#pragma unroll
        for (int r = 0; r < 4; ++r) pmax = fmaxf(pmax, sc[t][r]);
      if (!__all(pmax <= m_run + 10.f)) {
        pmax = fmaxf(pmax, __shfl_xor(pmax, 16));
        pmax = fmaxf(pmax, __shfl_xor(pmax, 32));
        float mnew = fmaxf(m_run, pmax);
        float corr = exp2f(m_run - mnew);
        m_run = mnew;
        float corro[4];
#pragma unroll
        for (int r = 0; r < 4; ++r) corro[r] = __shfl(corr, 4 * g + r);
#pragma unroll
        for (int dt = 0; dt < 9; ++dt)
#pragma unroll
          for (int r = 0; r < 4; ++r) acc[dt][r] *= corro[r];
      }
      // ---- P -> fp16, transpose through per-wave LDS ----
      ushort4 wh;
#pragma unroll
      for (int t = 0; t < 4; ++t) {
        wh.x = f2h(exp2f(sc[t][0] - m_run));
        wh.y = f2h(exp2f(sc[t][1] - m_run));
        wh.z = f2h(exp2f(sc[t][2] - m_run));
        wh.w = f2h(exp2f(sc[t][3] - m_run));
        *(ushort4*)&Plds[wave][l15][16 * t + 4 * g] = wh;
      }
      half8 pa0 = s2h(*(const short8*)&Plds[wave][l15][8 * g]);
      half8 pa1 = s2h(*(const short8*)&Plds[wave][l15][32 + 8 * g]);
      // ---- PV (fp16): 2 k-halves per d-tile + l via constant-ones ----
      __builtin_amdgcn_s_setprio(1);
#pragma unroll
      for (int dt = 0; dt < 8; ++dt) {
        int d = dt * 16 + l15;
        int rbase = d * 128, sw = (d & 7) << 4;
        half8 v0 = s2h(*(const short8*)(Vb + rbase + ((g * 16) ^ sw)));
        half8 v1 = s2h(*(const short8*)(Vb + rbase + ((64 + g * 16) ^ sw)));
        acc[dt] = __builtin_amdgcn_mfma_f32_16x16x32_f16(pa0, v0, acc[dt], 0, 0, 0);
        acc[dt] = __builtin_amdgcn_mfma_f32_16x16x32_f16(pa1, v1, acc[dt], 0, 0, 0);
      }
      acc[8] = __builtin_amdgcn_mfma_f32_16x16x32_f16(pa0, vones, acc[8], 0, 0, 0);
      acc[8] = __builtin_amdgcn_mfma_f32_16x16x32_f16(pa1, vones, acc[8], 0, 0, 0);
      __builtin_amdgcn_s_setprio(0);
    }
    asm volatile("s_waitcnt vmcnt(0)" ::: "memory");   // next buf landed (covered)
    __builtin_amdgcn_s_barrier();
    __builtin_amdgcn_sched_barrier(0);
    buf ^= 1;
  }
#undef STAGE64

  float linv[4];
#pragma unroll
  for (int r = 0; r < 4; ++r) linv[r] = 1.f / acc[8][r];
#pragma unroll
  for (int r = 0; r < 4; ++r) {
    size_t orow = ((size_t)(b * SEQ + q0w + 4 * g + r) * NHQ + h) * HDD + l15;
#pragma unroll
    for (int dt = 0; dt < 8; ++dt)
      o[orow + dt * 16] = acc[dt][r] * linv[r];
  }
}

// ---------------------------------------------------------------------------
extern "C" void kernel_launch(void* const* d_in, const int* in_sizes, int n_in,
                              void* d_out, int out_size, void* d_ws, size_t ws_size,
                              hipStream_t stream) {
  const float* x  = (const float*)d_in[0];
  const float* cs = (const float*)d_in[1];
  const float* sn = (const float*)d_in[2];
  const float* wq = (const float*)d_in[3];
  const float* wk = (const float*)d_in[4];
  const float* wv = (const float*)d_in[5];
  const float* wo = (const float*)d_in[6];
  const float* qn = (const float*)d_in[7];
  const float* kn = (const float*)d_in[8];
  float* out = (float*)d_out;
  char* ws = (char*)d_ws;

  const size_t MB = 1024 * 1024;
  size_t o_xq  = 0;            // 4 MB  int8 xq
  size_t o_wqk = 4  * MB;      // 6 MB  [3072][2048] i8
  size_t o_wvt = 10 * MB;      // 2 MB  [1024][2048] i8
  size_t o_wot = 12 * MB;      // 4 MB  [2048][2048] i8
  size_t o_vt  = 16 * MB;      // 4 MB  fp16 V transposed
  size_t o_qf  = 20 * MB;      // 8 MB  fp16 q (rope'd, log2e/sqrt(128) folded)
  size_t o_kf  = 28 * MB;      // 4 MB  fp16 k (rope'd)
  size_t o_ao  = 32 * MB;      // 16 MB f32 attn out
  size_t o_aq  = 48 * MB;      // 4 MB  int8 requant
  size_t o_as  = 52 * MB;
  size_t o_as2 = o_as  + 8192;
  size_t o_prt = o_as2 + 8192;
  size_t o_wsc = o_prt + 8192;

  signed char* xq  = (signed char*)(ws + o_xq);
  signed char* wqk = (signed char*)(ws + o_wqk);
  signed char* wvt = (signed char*)(ws + o_wvt);
  signed char* wot = (signed char*)(ws + o_wot);
  unsigned short* vt = (unsigned short*)(ws + o_vt);
  unsigned short* qf = (unsigned short*)(ws + o_qf);
  unsigned short* kf = (unsigned short*)(ws + o_kf);
  float* ao = (float*)(ws + o_ao);
  signed char* aq = (signed char*)(ws + o_aq);
  float* asx = (float*)(ws + o_as);
  float* as2 = (float*)(ws + o_as2);
  double* prt = (double*)(ws + o_prt);
  float* wsc = (float*)(ws + o_wsc);

  // 1) act quant of x + weight |w| partials (one dispatch)
  k_quant_stats<<<3072, 256, 0, stream>>>(x, xq, asx, wq, wk, wv, wo, prt);

  // 2) ternary quant of wq/wk/wv (publishes wsc)
  k_wquant_all<<<1024, 256, 0, stream>>>(wq, wk, wv, wqk, wvt, prt, wsc);

  // 3) fused QKV projection + rmsnorm/rope epilogue (128x128, BK=128)
  k_gemm_i8<<<512, 256, 0, stream>>>(xq, wqk, wvt, vt, asx, wsc,
                                     qn, kn, cs, sn, qf, kf);

  // 4) MFMA flash attention (KV tile 64, pure attention)
  k_attn_mfma<<<512, 256, 0, stream>>>(qf, kf, vt, ao);

  // 5) re-quant (+ wot quant hosted in tail blocks) + output projection
  k_actquant<<<2176, 256, 0, stream>>>(ao, aq, as2, wsc, wo, wot);
  k_gemm_o<<<512, 256, 0, stream>>>(aq, wot, out, as2, wsc);
}

// Round 18
// 108.950 us; speedup vs baseline: 1.0933x; 1.0762x over previous
//
#include <hip/hip_runtime.h>
#include <hip/hip_bf16.h>

#define TT   2048   // B*S tokens
#define HH   2048   // hidden dim
#define SEQ  1024
#define NHQ  16
#define NKVH 8
#define HDD  128

typedef __attribute__((ext_vector_type(8))) short short8;
typedef __attribute__((ext_vector_type(4))) float f32x4;
typedef __attribute__((ext_vector_type(4))) int int4v;
typedef _Float16 half8 __attribute__((ext_vector_type(8)));

static __device__ __forceinline__ unsigned short f2h(float f) {
  union { _Float16 h; unsigned short u; } c;
  c.h = (_Float16)f;
  return c.u;
}
static __device__ __forceinline__ half8 s2h(short8 v) {
  union { short8 s; half8 h; } c;
  c.s = v;
  return c.h;
}

#define GLD_LDS16(gp, lp)                                                        \
  __builtin_amdgcn_global_load_lds(                                              \
      (const __attribute__((address_space(1))) void*)(const void*)(gp),          \
      (__attribute__((address_space(3))) void*)(void*)(lp), 16, 0, 0)

// ---------------------------------------------------------------------------
// K1: fused act_quant(x) + weight |w| partial sums, one dispatch.
// ---------------------------------------------------------------------------
__global__ __launch_bounds__(256) void k_quant_stats(const float* __restrict__ x,
                                                     signed char* __restrict__ xq,
                                                     float* __restrict__ as_inv,
                                                     const float* __restrict__ wq,
                                                     const float* __restrict__ wk,
                                                     const float* __restrict__ wv,
                                                     const float* __restrict__ wo,
                                                     double* __restrict__ part) {
  int tid = threadIdx.x;
  int wave = tid >> 6, lane = tid & 63;
  __shared__ double redd[256];
  __shared__ float wred[4];

  if (blockIdx.x < 2048) {
    int row = blockIdx.x;
    const float4* xr4 = (const float4*)(x + (size_t)row * HH);
    float4 a = xr4[tid * 2], b = xr4[tid * 2 + 1];
    float am = fmaxf(fmaxf(fmaxf(fabsf(a.x), fabsf(a.y)), fmaxf(fabsf(a.z), fabsf(a.w))),
                     fmaxf(fmaxf(fabsf(b.x), fabsf(b.y)), fmaxf(fabsf(b.z), fabsf(b.w))));
#pragma unroll
    for (int o = 32; o; o >>= 1) am = fmaxf(am, __shfl_xor(am, o));
    if (lane == 0) wred[wave] = am;
    __syncthreads();
    am = fmaxf(fmaxf(wred[0], wred[1]), fmaxf(wred[2], wred[3]));
    am = fmaxf(am, 1e-5f);
    if (tid == 0) as_inv[row] = am / 127.f;
    float scale = 127.f / am;
    float vals[8] = {a.x, a.y, a.z, a.w, b.x, b.y, b.z, b.w};
    unsigned int u0 = 0, u1 = 0;
#pragma unroll
    for (int j = 0; j < 4; ++j) {
      int q = (int)fminf(fmaxf(rintf(vals[j] * scale), -128.f), 127.f);
      u0 |= (unsigned int)(q & 255) << (8 * j);
    }
#pragma unroll
    for (int j = 0; j < 4; ++j) {
      int q = (int)fminf(fmaxf(rintf(vals[4 + j] * scale), -128.f), 127.f);
      u1 |= (unsigned int)(q & 255) << (8 * j);
    }
    uint2 uu; uu.x = u0; uu.y = u1;
    ((uint2*)(xq + (size_t)row * HH))[tid] = uu;
  } else {
    int idx = blockIdx.x - 2048;
    int wid = idx >> 8, sub = idx & 255;
    const float* w = (wid == 0) ? wq : (wid == 1) ? wk : (wid == 2) ? wv : wo;
    int nq = ((wid == 0 || wid == 3) ? 4194304 : 2097152) >> 2;
    double s = 0.0;
    for (int i = sub * 256 + tid; i < nq; i += 256 * 256) {
      float4 v = ((const float4*)w)[i];
      s += (double)fabsf(v.x) + (double)fabsf(v.y) + (double)fabsf(v.z) + (double)fabsf(v.w);
    }
    redd[tid] = s;
    __syncthreads();
    for (int st = 128; st > 0; st >>= 1) {
      if (tid < st) redd[tid] += redd[tid + st];
      __syncthreads();
    }
    if (tid == 0) part[wid * 256 + sub] = redd[0];
  }
}

// ---------------------------------------------------------------------------
// K3: ternary weight quant -> int8 for wq,wk,wv. Block 0 publishes wsc.
// ---------------------------------------------------------------------------
__global__ __launch_bounds__(256) void k_wquant_all(const float* __restrict__ wq,
                                                    const float* __restrict__ wk,
                                                    const float* __restrict__ wv,
                                                    signed char* __restrict__ wqk,
                                                    signed char* __restrict__ wvt,
                                                    const double* __restrict__ part,
                                                    float* __restrict__ wsc) {
  int tid = threadIdx.x;
  int wave = tid >> 6, lane = tid & 63;
  __shared__ double wred[4][4];
  __shared__ float s_wsc[4];
  const double nvals[4] = {4194304.0, 2097152.0, 2097152.0, 4194304.0};
#pragma unroll
  for (int w = 0; w < 4; ++w) {
    double s = part[w * 256 + tid];
#pragma unroll
    for (int o = 32; o; o >>= 1) s += __shfl_xor(s, o);
    if (lane == 0) wred[w][wave] = s;
  }
  __syncthreads();
  if (tid < 4) {
    double s = (wred[tid][0] + wred[tid][1]) + (wred[tid][2] + wred[tid][3]);
    float v = fmaxf((float)(s / nvals[tid]), 1e-5f);
    s_wsc[tid] = v;
    if (blockIdx.x == 0) wsc[tid] = v;
  }
  __syncthreads();
  float inv0 = 1.f / s_wsc[0], inv1 = 1.f / s_wsc[1], inv2 = 1.f / s_wsc[2];

  const int NQ = 2097152;   // wq(1048576) + wk(524288) + wv(524288) quads
  for (int qi = blockIdx.x * 256 + tid; qi < NQ; qi += gridDim.x * 256) {
    const float* src; signed char* dst; float inv; int off;
    if (qi < 1048576)      { src = wq; dst = wqk;           off = qi;           inv = inv0; }
    else if (qi < 1572864) { src = wk; dst = wqk + 4194304; off = qi - 1048576; inv = inv1; }
    else                   { src = wv; dst = wvt;           off = qi - 1572864; inv = inv2; }
    float4 v = ((const float4*)src)[off];
    unsigned int u = 0;
    float vv[4] = {v.x, v.y, v.z, v.w};
#pragma unroll
    for (int j = 0; j < 4; ++j) {
      int q = (int)fminf(fmaxf(rintf(vv[j] * inv), -1.f), 1.f);
      u |= (unsigned int)(q & 255) << (8 * j);
    }
    ((unsigned int*)dst)[off] = u;
  }
}

// ---------------------------------------------------------------------------
// K4: QKV i8 MFMA NT-GEMM, 128x128 tile, BK=128, 2-buffer stage-at-top
// pipeline, 8-way XOR swizzle, 512 blocks.
// ---------------------------------------------------------------------------
__global__ __launch_bounds__(256) void k_gemm_i8(const signed char* __restrict__ A0,
                                                 const signed char* __restrict__ B0,
                                                 const signed char* __restrict__ B1,
                                                 unsigned short* __restrict__ dh,
                                                 const float* __restrict__ asx,
                                                 const float* __restrict__ wsc,
                                                 const float* __restrict__ qn,
                                                 const float* __restrict__ kn,
                                                 const float* __restrict__ cs,
                                                 const float* __restrict__ sn,
                                                 unsigned short* __restrict__ qf,
                                                 unsigned short* __restrict__ kf) {
  const int K = HH;
  __shared__ signed char As[2][16384];   // [buf][128][128] swizzled rows
  __shared__ signed char Bs[2][16384];
  int tid = threadIdx.x;
  int wave = tid >> 6, lane = tid & 63, l15 = lane & 15, g = lane >> 4;
  int wm = wave >> 1, wn = wave & 1;

  int gid = (blockIdx.x & 7) * 64 + (blockIdx.x >> 3);   // XCD chunk, 512 blocks
  const signed char *Ap, *Bp;
  int bm, bn, mode;
  if (gid < 384) { mode = 0; bm = (gid / 24) * 128; bn = (gid % 24) * 128; Ap = A0; Bp = B0; }
  else { mode = 1; int vid = gid - 384; bm = (vid >> 4) * 128; bn = (vid & 15) * 128; Ap = B1; Bp = A0; }

#define GSTAGE(K0, BUF)                                                               \
  {                                                                                   \
    _Pragma("unroll")                                                                 \
    for (int r = 0; r < 4; ++r) {                                                     \
      int c = r * 256 + tid;                                                          \
      int row = c >> 3;                                                               \
      int kk2 = ((c & 7) << 4) ^ ((row & 7) << 4);                                    \
      GLD_LDS16(Ap + (size_t)(bm + row) * K + (K0) + kk2, As[BUF] + c * 16);          \
      GLD_LDS16(Bp + (size_t)(bn + row) * K + (K0) + kk2, Bs[BUF] + c * 16);          \
    }                                                                                 \
  }

  int4v acc[4][4] = {};
  GSTAGE(0, 0);
  asm volatile("s_waitcnt vmcnt(0)" ::: "memory");
  __builtin_amdgcn_s_barrier();
  __builtin_amdgcn_sched_barrier(0);

  int buf = 0;
  for (int k0 = 0; k0 < K; k0 += 128) {
    bool more = (k0 + 128 < K);
    if (more) GSTAGE(k0 + 128, buf ^ 1);   // issued early; compute covers latency
#pragma unroll
    for (int ks = 0; ks < 2; ++ks) {
      int4v af[4], bf[4];
#pragma unroll
      for (int i = 0; i < 4; ++i) {
        int ra = wm * 64 + i * 16 + l15;
        af[i] = *(const int4v*)&As[buf][ra * 128 + ((ks * 64 + g * 16) ^ ((ra & 7) << 4))];
        int rb = (mode == 0) ? (wn * 32 + (i & 1) * 16 + (i >> 1) * 64 + l15)
                             : (wn * 64 + i * 16 + l15);
        bf[i] = *(const int4v*)&Bs[buf][rb * 128 + ((ks * 64 + g * 16) ^ ((rb & 7) << 4))];
      }
      __builtin_amdgcn_s_setprio(1);
#pragma unroll
      for (int mi = 0; mi < 4; ++mi)
#pragma unroll
        for (int ni = 0; ni < 4; ++ni)
          acc[mi][ni] = __builtin_amdgcn_mfma_i32_16x16x64_i8(af[mi], bf[ni], acc[mi][ni], 0, 0, 0);
      __builtin_amdgcn_s_setprio(0);
    }
    asm volatile("s_waitcnt vmcnt(0)" ::: "memory");
    __builtin_amdgcn_s_barrier();
    __builtin_amdgcn_sched_barrier(0);
    buf ^= 1;
  }
#undef GSTAGE

  if (mode == 0) {
    // fused rmsnorm + rope epilogue -> single fp16
    bool isq = (bn < 2048);
    int hh = isq ? (bn >> 7) : ((bn - 2048) >> 7);
    float wN = isq ? wsc[0] : wsc[1];
    float ps = isq ? 0.12751743075f : 1.0f;   // (1/sqrt(128))*log2(e) for q
    const float* nw = isq ? qn : kn;
    unsigned short* oh = isq ? qf : kf;
    int nhp = isq ? NHQ : NKVH;
    float* S = (float*)&As[0][0];        // reuse LDS: [2][128] f32
    __syncthreads();
#pragma unroll
    for (int mi = 0; mi < 4; ++mi) {
#pragma unroll
      for (int rr = 0; rr < 4; ++rr) {
        int tok = bm + wm * 64 + mi * 16 + 4 * g + rr;
        float rs = asx[tok] * wN;
        float ssum = 0.f;
#pragma unroll
        for (int ni = 0; ni < 4; ++ni) {
          float v = (float)acc[mi][ni][rr] * rs;
          ssum += v * v;
        }
        ssum += __shfl_xor(ssum, 1); ssum += __shfl_xor(ssum, 2);
        ssum += __shfl_xor(ssum, 4); ssum += __shfl_xor(ssum, 8);
        if (l15 == 0) S[wn * 128 + wm * 64 + mi * 16 + 4 * g + rr] = ssum;
      }
    }
    __syncthreads();
#pragma unroll
    for (int mi = 0; mi < 4; ++mi) {
#pragma unroll
      for (int rr = 0; rr < 4; ++rr) {
        int rloc = wm * 64 + mi * 16 + 4 * g + rr;
        int tok = bm + rloc;
        float rs = asx[tok] * wN;
        float inv = rsqrtf((S[rloc] + S[128 + rloc]) * (1.f / 128.f) + 1e-6f);
        int s = tok & (SEQ - 1);
        float nv[4];
#pragma unroll
        for (int ni = 0; ni < 4; ++ni) {
          int d = wn * 32 + (ni & 1) * 16 + (ni >> 1) * 64 + l15;
          nv[ni] = nw[d] * ((float)acc[mi][ni][rr] * rs) * inv;
        }
#pragma unroll
        for (int ni = 0; ni < 4; ++ni) {
          int d = wn * 32 + (ni & 1) * 16 + (ni >> 1) * 64 + l15;
          float oo = nv[ni ^ 2];
          float rh = (ni < 2) ? -oo : oo;
          float res = (nv[ni] * cs[s * 128 + d] + rh * sn[s * 128 + d]) * ps;
          size_t oi = ((size_t)tok * nhp + hh) * 128 + d;
          oh[oi] = f2h(res);
        }
      }
    }
  } else {   // mode 1: V fp16 transposed (crow=feature, ccol=token)
    float w2 = wsc[2];
#pragma unroll
    for (int mi = 0; mi < 4; ++mi) {
#pragma unroll
      for (int rr = 0; rr < 4; ++rr) {
        int crow = bm + wm * 64 + mi * 16 + 4 * g + rr;
#pragma unroll
        for (int ni = 0; ni < 4; ++ni) {
          int ccol = bn + wn * 64 + ni * 16 + l15;
          float v = (float)acc[mi][ni][rr] * asx[ccol] * w2;
          size_t ad = ((size_t)((ccol >> 10) * 1024 + crow)) * 1024 + (ccol & 1023);
          dh[ad] = f2h(v);
        }
      }
    }
  }
}

// ---------------------------------------------------------------------------
// K4b: O projection, 128x64 tiles, BK=128, 512 blocks, 2-buffer pipeline.
// ---------------------------------------------------------------------------
__global__ __launch_bounds__(256) void k_gemm_o(const signed char* __restrict__ A,
                                                const signed char* __restrict__ B,
                                                float* __restrict__ d0,
                                                const float* __restrict__ asx,
                                                const float* __restrict__ wsc) {
  const int K = HH;
  __shared__ signed char As[2][16384];   // [buf][128][128]
  __shared__ signed char Bs[2][8192];    // [buf][64][128]
  int tid = threadIdx.x;
  int wave = tid >> 6, lane = tid & 63, l15 = lane & 15, g = lane >> 4;
  int gid = (blockIdx.x & 7) * 64 + (blockIdx.x >> 3);
  int bm = (gid >> 5) * 128, bn = (gid & 31) * 64;

#define OSTAGE(K0, BUF)                                                               \
  {                                                                                   \
    _Pragma("unroll")                                                                 \
    for (int r = 0; r < 4; ++r) {                                                     \
      int c = r * 256 + tid;                                                          \
      int row = c >> 3;                                                               \
      int kk2 = ((c & 7) << 4) ^ ((row & 7) << 4);                                    \
      GLD_LDS16(A + (size_t)(bm + row) * K + (K0) + kk2, As[BUF] + c * 16);           \
    }                                                                                 \
    _Pragma("unroll")                                                                 \
    for (int r = 0; r < 2; ++r) {                                                     \
      int c = r * 256 + tid;                                                          \
      int row = c >> 3;                                                               \
      int kk2 = ((c & 7) << 4) ^ ((row & 7) << 4);                                    \
      GLD_LDS16(B + (size_t)(bn + row) * K + (K0) + kk2, Bs[BUF] + c * 16);           \
    }                                                                                 \
  }

  int4v acc[2][4] = {};
  OSTAGE(0, 0);
  asm volatile("s_waitcnt vmcnt(0)" ::: "memory");
  __builtin_amdgcn_s_barrier();
  __builtin_amdgcn_sched_barrier(0);

  int buf = 0;
  for (int k0 = 0; k0 < K; k0 += 128) {
    bool more = (k0 + 128 < K);
    if (more) OSTAGE(k0 + 128, buf ^ 1);
#pragma unroll
    for (int ks = 0; ks < 2; ++ks) {
      int4v af[2], bf[4];
#pragma unroll
      for (int i = 0; i < 2; ++i) {
        int ra = wave * 32 + i * 16 + l15;
        af[i] = *(const int4v*)&As[buf][ra * 128 + ((ks * 64 + g * 16) ^ ((ra & 7) << 4))];
      }
#pragma unroll
      for (int n = 0; n < 4; ++n) {
        int rb = n * 16 + l15;
        bf[n] = *(const int4v*)&Bs[buf][rb * 128 + ((ks * 64 + g * 16) ^ ((rb & 7) << 4))];
      }
      __builtin_amdgcn_s_setprio(1);
#pragma unroll
      for (int mi = 0; mi < 2; ++mi)
#pragma unroll
        for (int ni = 0; ni < 4; ++ni)
          acc[mi][ni] = __builtin_amdgcn_mfma_i32_16x16x64_i8(af[mi], bf[ni], acc[mi][ni], 0, 0, 0);
      __builtin_amdgcn_s_setprio(0);
    }
    asm volatile("s_waitcnt vmcnt(0)" ::: "memory");
    __builtin_amdgcn_s_barrier();
    __builtin_amdgcn_sched_barrier(0);
    buf ^= 1;
  }
#undef OSTAGE

  float w3 = wsc[3];
#pragma unroll
  for (int mi = 0; mi < 2; ++mi) {
#pragma unroll
    for (int rr = 0; rr < 4; ++rr) {
      int crow = bm + wave * 32 + mi * 16 + 4 * g + rr;
      float rs = asx[crow] * w3;
#pragma unroll
      for (int ni = 0; ni < 4; ++ni) {
        int ccol = bn + ni * 16 + l15;
        d0[(size_t)crow * 2048 + ccol] = (float)acc[mi][ni][rr] * rs;
      }
    }
  }
}

// ---------------------------------------------------------------------------
// K5: per-row act_quant for requant of attn out
// ---------------------------------------------------------------------------
__global__ __launch_bounds__(256) void k_actquant(const float* __restrict__ x,
                                                  signed char* __restrict__ xq,
                                                  float* __restrict__ as_inv) {
  int row = blockIdx.x, tid = threadIdx.x;
  int wave = tid >> 6, lane = tid & 63;
  const float4* xr4 = (const float4*)(x + (size_t)row * HH);
  float4 a = xr4[tid * 2], b = xr4[tid * 2 + 1];
  float am = fmaxf(fmaxf(fmaxf(fabsf(a.x), fabsf(a.y)), fmaxf(fabsf(a.z), fabsf(a.w))),
                   fmaxf(fmaxf(fabsf(b.x), fabsf(b.y)), fmaxf(fabsf(b.z), fabsf(b.w))));
#pragma unroll
  for (int o = 32; o; o >>= 1) am = fmaxf(am, __shfl_xor(am, o));
  __shared__ float wred[4];
  if (lane == 0) wred[wave] = am;
  __syncthreads();
  am = fmaxf(fmaxf(wred[0], wred[1]), fmaxf(wred[2], wred[3]));
  am = fmaxf(am, 1e-5f);
  if (tid == 0) as_inv[row] = am / 127.f;
  float scale = 127.f / am;
  float vals[8] = {a.x, a.y, a.z, a.w, b.x, b.y, b.z, b.w};
  unsigned int u0 = 0, u1 = 0;
#pragma unroll
  for (int j = 0; j < 4; ++j) {
    int q = (int)fminf(fmaxf(rintf(vals[j] * scale), -128.f), 127.f);
    u0 |= (unsigned int)(q & 255) << (8 * j);
  }
#pragma unroll
  for (int j = 0; j < 4; ++j) {
    int q = (int)fminf(fmaxf(rintf(vals[4 + j] * scale), -128.f), 127.f);
    u1 |= (unsigned int)(q & 255) << (8 * j);
  }
  uint2 uu; uu.x = u0; uu.y = u1;
  ((uint2*)(xq + (size_t)row * HH))[tid] = uu;
}

// ---------------------------------------------------------------------------
// K6: MFMA flash attention, KV tile 64, 2-buffer stage-at-top pipeline,
// balanced CU pairing. Hosts wot quant in blocks 512..639 (overlaps the
// attention window, where HBM is nearly idle).
// ---------------------------------------------------------------------------
__global__ __launch_bounds__(256) void k_attn_mfma(const unsigned short* __restrict__ qfp,
                                                   const unsigned short* __restrict__ kfp,
                                                   const unsigned short* __restrict__ vfp,
                                                   float* __restrict__ o,
                                                   const float* __restrict__ wsc,
                                                   const float* __restrict__ wo_f32,
                                                   signed char* __restrict__ wot) {
  int tid = threadIdx.x;
  if (blockIdx.x >= 512) {
    int bx = blockIdx.x - 512;          // 0..127
    float inv = 1.f / wsc[3];
    for (int qi = bx * 256 + tid; qi < 1048576; qi += 128 * 256) {
      float4 v = ((const float4*)wo_f32)[qi];
      unsigned int u = 0;
      float vv[4] = {v.x, v.y, v.z, v.w};
#pragma unroll
      for (int j = 0; j < 4; ++j) {
        int q = (int)fminf(fmaxf(rintf(vv[j] * inv), -1.f), 1.f);
        u |= (unsigned int)(q & 255) << (8 * j);
      }
      ((unsigned int*)wot)[qi] = u;
    }
    return;
  }

  int chunk = blockIdx.x & 7, j = blockIdx.x >> 3;   // XCD, within-chunk
  int qt, yyi;
  if (j < 32) { qt = 15 - (j >> 2); yyi = j & 3; }          // heavy half first
  else        { qt = (j - 32) >> 2; yyi = (j - 32) & 3; }   // paired light half
  int yy = (chunk << 2) + yyi;
  int b = yy >> 4, h = yy & 15, kvh = h >> 1;
  int wave = tid >> 6, lane = tid & 63;
  int l15 = lane & 15, g = lane >> 4;
  int q0w = qt * 64 + wave * 16;
  int qglob = q0w + l15;

  __shared__ unsigned short Kf[2][8192];     // fp16 K, [ki(64)][d(128)] swizzled
  __shared__ unsigned short Vf[2][8192];     // fp16 V^T [d(128)][tok(64)] swizzled
  __shared__ unsigned short Plds[4][16][72]; // fp16 P, 64 keys + pad

  half8 qf[4];
  {
    const unsigned short* qb = qfp + ((size_t)(b * SEQ + qglob) * NHQ + h) * HDD + g * 8;
#pragma unroll
    for (int c = 0; c < 4; ++c) qf[c] = s2h(*(const short8*)(qb + c * 32));
  }
  half8 vones;
#pragma unroll
  for (int c = 0; c < 8; ++c) vones[c] = (_Float16)1.0f;

#define STAGE64(KV0N, BUF)                                                            \
  {                                                                                   \
    _Pragma("unroll")                                                                 \
    for (int tch = 0; tch < 4; ++tch) {                                               \
      int c = tch * 256 + tid;                                                        \
      int ki = c >> 4, jb = (c & 15) << 4;                                            \
      int js = jb ^ ((ki & 7) << 4);                                                  \
      size_t kbase = ((size_t)(b * SEQ + (KV0N) + ki) * NKVH + kvh) * HDD;            \
      GLD_LDS16((const char*)(kfp + kbase) + js, &Kf[BUF][c * 8]);                    \
      int d = c >> 3, jv = (c & 7) << 4;                                              \
      int jvs = jv ^ ((d & 7) << 4);                                                  \
      size_t vbase = ((size_t)(b * 1024 + kvh * 128 + d)) * SEQ + (KV0N);             \
      GLD_LDS16((const char*)(vfp + vbase) + jvs, &Vf[BUF][c * 8]);                   \
    }                                                                                 \
  }

  f32x4 acc[9] = {};                 // [0..7]=O d-tiles, [8]=l (ones-V)
  float m_run = -INFINITY;
  int nkv = qt + 1;                  // 64-key tiles

  STAGE64(0, 0);
  asm volatile("s_waitcnt vmcnt(0) lgkmcnt(0)" ::: "memory");
  __builtin_amdgcn_s_barrier();
  __builtin_amdgcn_sched_barrier(0);

  int buf = 0;
  for (int kv = 0; kv < nkv; ++kv) {
    int kv0 = kv * 64;
    bool more = (kv + 1 < nkv);
    if (more) STAGE64(kv0 + 64, buf ^ 1);   // issued early; compute covers latency
    bool active = (kv0 <= q0w + 15);
    if (active) {
      const char* Kb = (const char*)&Kf[buf][0];
      const char* Vb = (const char*)&Vf[buf][0];
      // ---- QK^T (fp16, scores in log2 units): 4 tiles of 16 keys ----
      float sc[4][4];
      __builtin_amdgcn_s_setprio(1);
#pragma unroll
      for (int t = 0; t < 4; ++t) {
        int row = 16 * t + l15;
        int rbyte = row * 256, sw = (row & 7) << 4;
        f32x4 s = {0.f, 0.f, 0.f, 0.f};
#pragma unroll
        for (int c = 0; c < 4; ++c) {
          int off = rbyte + ((c * 64 + g * 16) ^ sw);
          half8 kf8 = s2h(*(const short8*)(Kb + off));
          s = __builtin_amdgcn_mfma_f32_16x16x32_f16(kf8, qf[c], s, 0, 0, 0);
        }
#pragma unroll
        for (int r = 0; r < 4; ++r) sc[t][r] = s[r];
      }
      __builtin_amdgcn_s_setprio(0);
      if (kv0 + 63 > q0w) {
#pragma unroll
        for (int t = 0; t < 4; ++t)
#pragma unroll
          for (int r = 0; r < 4; ++r)
            if (kv0 + 16 * t + 4 * g + r > qglob) sc[t][r] = -INFINITY;
      }
      // ---- online softmax (exp2; defer-max, per-lane check) ----
      float pmax = -INFINITY;
#pragma unroll
      for (int t = 0; t < 4; ++t)
#pragma unroll
        for (int r = 0; r < 4; ++r) pmax = fmaxf(pmax, sc[t][r]);
      if (!__all(pmax <= m_run + 10.f)) {
        pmax = fmaxf(pmax, __shfl_xor(pmax, 16));
        pmax = fmaxf(pmax, __shfl_xor(pmax, 32));
        float mnew = fmaxf(m_run, pmax);
        float corr = exp2f(m_run - mnew);
        m_run = mnew;
        float corro[4];
#pragma unroll
        for (int r = 0; r < 4; ++r) corro[r] = __shfl(corr, 4 * g + r);
#pragma unroll
        for (int dt = 0; dt < 9; ++dt)
#pragma unroll
          for (int r = 0; r < 4; ++r) acc[dt][r] *= corro[r];
      }
      // ---- P -> fp16, transpose through per-wave LDS ----
      ushort4 wh;
#pragma unroll
      for (int t = 0; t < 4; ++t) {
        wh.x = f2h(exp2f(sc[t][0] - m_run));
        wh.y = f2h(exp2f(sc[t][1] - m_run));
        wh.z = f2h(exp2f(sc[t][2] - m_run));
        wh.w = f2h(exp2f(sc[t][3] - m_run));
        *(ushort4*)&Plds[wave][l15][16 * t + 4 * g] = wh;
      }
      half8 pa0 = s2h(*(const short8*)&Plds[wave][l15][8 * g]);
      half8 pa1 = s2h(*(const short8*)&Plds[wave][l15][32 + 8 * g]);
      // ---- PV (fp16): 2 k-halves per d-tile + l via constant-ones ----
      __builtin_amdgcn_s_setprio(1);
#pragma unroll
      for (int dt = 0; dt < 8; ++dt) {
        int d = dt * 16 + l15;
        int rbase = d * 128, sw = (d & 7) << 4;
        half8 v0 = s2h(*(const short8*)(Vb + rbase + ((g * 16) ^ sw)));
        half8 v1 = s2h(*(const short8*)(Vb + rbase + ((64 + g * 16) ^ sw)));
        acc[dt] = __builtin_amdgcn_mfma_f32_16x16x32_f16(pa0, v0, acc[dt], 0, 0, 0);
        acc[dt] = __builtin_amdgcn_mfma_f32_16x16x32_f16(pa1, v1, acc[dt], 0, 0, 0);
      }
      acc[8] = __builtin_amdgcn_mfma_f32_16x16x32_f16(pa0, vones, acc[8], 0, 0, 0);
      acc[8] = __builtin_amdgcn_mfma_f32_16x16x32_f16(pa1, vones, acc[8], 0, 0, 0);
      __builtin_amdgcn_s_setprio(0);
    }
    asm volatile("s_waitcnt vmcnt(0)" ::: "memory");   // next buf landed (covered)
    __builtin_amdgcn_s_barrier();
    __builtin_amdgcn_sched_barrier(0);
    buf ^= 1;
  }
#undef STAGE64

  float linv[4];
#pragma unroll
  for (int r = 0; r < 4; ++r) linv[r] = 1.f / acc[8][r];
#pragma unroll
  for (int r = 0; r < 4; ++r) {
    size_t orow = ((size_t)(b * SEQ + q0w + 4 * g + r) * NHQ + h) * HDD + l15;
#pragma unroll
    for (int dt = 0; dt < 8; ++dt)
      o[orow + dt * 16] = acc[dt][r] * linv[r];
  }
}

// ---------------------------------------------------------------------------
extern "C" void kernel_launch(void* const* d_in, const int* in_sizes, int n_in,
                              void* d_out, int out_size, void* d_ws, size_t ws_size,
                              hipStream_t stream) {
  const float* x  = (const float*)d_in[0];
  const float* cs = (const float*)d_in[1];
  const float* sn = (const float*)d_in[2];
  const float* wq = (const float*)d_in[3];
  const float* wk = (const float*)d_in[4];
  const float* wv = (const float*)d_in[5];
  const float* wo = (const float*)d_in[6];
  const float* qn = (const float*)d_in[7];
  const float* kn = (const float*)d_in[8];
  float* out = (float*)d_out;
  char* ws = (char*)d_ws;

  const size_t MB = 1024 * 1024;
  size_t o_xq  = 0;            // 4 MB  int8 xq
  size_t o_wqk = 4  * MB;      // 6 MB  [3072][2048] i8
  size_t o_wvt = 10 * MB;      // 2 MB  [1024][2048] i8
  size_t o_wot = 12 * MB;      // 4 MB  [2048][2048] i8
  size_t o_vt  = 16 * MB;      // 4 MB  fp16 V transposed
  size_t o_qf  = 20 * MB;      // 8 MB  fp16 q (rope'd, log2e/sqrt(128) folded)
  size_t o_kf  = 28 * MB;      // 4 MB  fp16 k (rope'd)
  size_t o_ao  = 32 * MB;      // 16 MB f32 attn out
  size_t o_aq  = 48 * MB;      // 4 MB  int8 requant
  size_t o_as  = 52 * MB;
  size_t o_as2 = o_as  + 8192;
  size_t o_prt = o_as2 + 8192;
  size_t o_wsc = o_prt + 8192;

  signed char* xq  = (signed char*)(ws + o_xq);
  signed char* wqk = (signed char*)(ws + o_wqk);
  signed char* wvt = (signed char*)(ws + o_wvt);
  signed char* wot = (signed char*)(ws + o_wot);
  unsigned short* vt = (unsigned short*)(ws + o_vt);
  unsigned short* qf = (unsigned short*)(ws + o_qf);
  unsigned short* kf = (unsigned short*)(ws + o_kf);
  float* ao = (float*)(ws + o_ao);
  signed char* aq = (signed char*)(ws + o_aq);
  float* asx = (float*)(ws + o_as);
  float* as2 = (float*)(ws + o_as2);
  double* prt = (double*)(ws + o_prt);
  float* wsc = (float*)(ws + o_wsc);

  // 1) act quant of x + weight |w| partials (one dispatch)
  k_quant_stats<<<3072, 256, 0, stream>>>(x, xq, asx, wq, wk, wv, wo, prt);

  // 2) ternary quant of wq/wk/wv (publishes wsc)
  k_wquant_all<<<1024, 256, 0, stream>>>(wq, wk, wv, wqk, wvt, prt, wsc);

  // 3) fused QKV projection + rmsnorm/rope epilogue (128x128, BK=128)
  k_gemm_i8<<<512, 256, 0, stream>>>(xq, wqk, wvt, vt, asx, wsc,
                                     qn, kn, cs, sn, qf, kf);

  // 4) MFMA flash attention (KV tile 64) + overlapped wot quant
  k_attn_mfma<<<640, 256, 0, stream>>>(qf, kf, vt, ao, wsc, wo, wot);

  // 5) re-quant + output projection (128x64, BK=128)
  k_actquant<<<TT, 256, 0, stream>>>(ao, aq, as2);
  k_gemm_o<<<512, 256, 0, stream>>>(aq, wot, out, as2, wsc);
}

// Round 19
// 107.635 us; speedup vs baseline: 1.1066x; 1.0122x over previous
//
#include <hip/hip_runtime.h>
#include <hip/hip_bf16.h>

#define TT   2048   // B*S tokens
#define HH   2048   // hidden dim
#define SEQ  1024
#define NHQ  16
#define NKVH 8
#define HDD  128

typedef __attribute__((ext_vector_type(8))) short short8;
typedef __attribute__((ext_vector_type(4))) float f32x4;
typedef __attribute__((ext_vector_type(4))) int int4v;
typedef _Float16 half8 __attribute__((ext_vector_type(8)));

static __device__ __forceinline__ unsigned short f2h(float f) {
  union { _Float16 h; unsigned short u; } c;
  c.h = (_Float16)f;
  return c.u;
}
static __device__ __forceinline__ float h2f(unsigned short u) {
  union { unsigned short u; _Float16 h; } c;
  c.u = u;
  return (float)c.h;
}
static __device__ __forceinline__ half8 s2h(short8 v) {
  union { short8 s; half8 h; } c;
  c.s = v;
  return c.h;
}

#define GLD_LDS16(gp, lp)                                                        \
  __builtin_amdgcn_global_load_lds(                                              \
      (const __attribute__((address_space(1))) void*)(const void*)(gp),          \
      (__attribute__((address_space(3))) void*)(void*)(lp), 16, 0, 0)

// ---------------------------------------------------------------------------
// K1: fused act_quant(x) + weight |w| partial sums, one dispatch.
// ---------------------------------------------------------------------------
__global__ __launch_bounds__(256) void k_quant_stats(const float* __restrict__ x,
                                                     signed char* __restrict__ xq,
                                                     float* __restrict__ as_inv,
                                                     const float* __restrict__ wq,
                                                     const float* __restrict__ wk,
                                                     const float* __restrict__ wv,
                                                     const float* __restrict__ wo,
                                                     double* __restrict__ part) {
  int tid = threadIdx.x;
  int wave = tid >> 6, lane = tid & 63;
  __shared__ double redd[256];
  __shared__ float wred[4];

  if (blockIdx.x < 2048) {
    int row = blockIdx.x;
    const float4* xr4 = (const float4*)(x + (size_t)row * HH);
    float4 a = xr4[tid * 2], b = xr4[tid * 2 + 1];
    float am = fmaxf(fmaxf(fmaxf(fabsf(a.x), fabsf(a.y)), fmaxf(fabsf(a.z), fabsf(a.w))),
                     fmaxf(fmaxf(fabsf(b.x), fabsf(b.y)), fmaxf(fabsf(b.z), fabsf(b.w))));
#pragma unroll
    for (int o = 32; o; o >>= 1) am = fmaxf(am, __shfl_xor(am, o));
    if (lane == 0) wred[wave] = am;
    __syncthreads();
    am = fmaxf(fmaxf(wred[0], wred[1]), fmaxf(wred[2], wred[3]));
    am = fmaxf(am, 1e-5f);
    if (tid == 0) as_inv[row] = am / 127.f;
    float scale = 127.f / am;
    float vals[8] = {a.x, a.y, a.z, a.w, b.x, b.y, b.z, b.w};
    unsigned int u0 = 0, u1 = 0;
#pragma unroll
    for (int j = 0; j < 4; ++j) {
      int q = (int)fminf(fmaxf(rintf(vals[j] * scale), -128.f), 127.f);
      u0 |= (unsigned int)(q & 255) << (8 * j);
    }
#pragma unroll
    for (int j = 0; j < 4; ++j) {
      int q = (int)fminf(fmaxf(rintf(vals[4 + j] * scale), -128.f), 127.f);
      u1 |= (unsigned int)(q & 255) << (8 * j);
    }
    uint2 uu; uu.x = u0; uu.y = u1;
    ((uint2*)(xq + (size_t)row * HH))[tid] = uu;
  } else {
    int idx = blockIdx.x - 2048;
    int wid = idx >> 8, sub = idx & 255;
    const float* w = (wid == 0) ? wq : (wid == 1) ? wk : (wid == 2) ? wv : wo;
    int nq = ((wid == 0 || wid == 3) ? 4194304 : 2097152) >> 2;
    double s = 0.0;
    for (int i = sub * 256 + tid; i < nq; i += 256 * 256) {
      float4 v = ((const float4*)w)[i];
      s += (double)fabsf(v.x) + (double)fabsf(v.y) + (double)fabsf(v.z) + (double)fabsf(v.w);
    }
    redd[tid] = s;
    __syncthreads();
    for (int st = 128; st > 0; st >>= 1) {
      if (tid < st) redd[tid] += redd[tid + st];
      __syncthreads();
    }
    if (tid == 0) part[wid * 256 + sub] = redd[0];
  }
}

// ---------------------------------------------------------------------------
// K3: ternary weight quant -> int8 for wq,wk,wv. Block 0 publishes wsc.
// ---------------------------------------------------------------------------
__global__ __launch_bounds__(256) void k_wquant_all(const float* __restrict__ wq,
                                                    const float* __restrict__ wk,
                                                    const float* __restrict__ wv,
                                                    signed char* __restrict__ wqk,
                                                    signed char* __restrict__ wvt,
                                                    const double* __restrict__ part,
                                                    float* __restrict__ wsc) {
  int tid = threadIdx.x;
  int wave = tid >> 6, lane = tid & 63;
  __shared__ double wred[4][4];
  __shared__ float s_wsc[4];
  const double nvals[4] = {4194304.0, 2097152.0, 2097152.0, 4194304.0};
#pragma unroll
  for (int w = 0; w < 4; ++w) {
    double s = part[w * 256 + tid];
#pragma unroll
    for (int o = 32; o; o >>= 1) s += __shfl_xor(s, o);
    if (lane == 0) wred[w][wave] = s;
  }
  __syncthreads();
  if (tid < 4) {
    double s = (wred[tid][0] + wred[tid][1]) + (wred[tid][2] + wred[tid][3]);
    float v = fmaxf((float)(s / nvals[tid]), 1e-5f);
    s_wsc[tid] = v;
    if (blockIdx.x == 0) wsc[tid] = v;
  }
  __syncthreads();
  float inv0 = 1.f / s_wsc[0], inv1 = 1.f / s_wsc[1], inv2 = 1.f / s_wsc[2];

  const int NQ = 2097152;   // wq(1048576) + wk(524288) + wv(524288) quads
  for (int qi = blockIdx.x * 256 + tid; qi < NQ; qi += gridDim.x * 256) {
    const float* src; signed char* dst; float inv; int off;
    if (qi < 1048576)      { src = wq; dst = wqk;           off = qi;           inv = inv0; }
    else if (qi < 1572864) { src = wk; dst = wqk + 4194304; off = qi - 1048576; inv = inv1; }
    else                   { src = wv; dst = wvt;           off = qi - 1572864; inv = inv2; }
    float4 v = ((const float4*)src)[off];
    unsigned int u = 0;
    float vv[4] = {v.x, v.y, v.z, v.w};
#pragma unroll
    for (int j = 0; j < 4; ++j) {
      int q = (int)fminf(fmaxf(rintf(vv[j] * inv), -1.f), 1.f);
      u |= (unsigned int)(q & 255) << (8 * j);
    }
    ((unsigned int*)dst)[off] = u;
  }
}

// ---------------------------------------------------------------------------
// K4: QKV i8 MFMA NT-GEMM, 128x128 tile, BK=128, 2-buffer stage-at-top
// pipeline, 8-way XOR swizzle, 512 blocks.
// ---------------------------------------------------------------------------
__global__ __launch_bounds__(256) void k_gemm_i8(const signed char* __restrict__ A0,
                                                 const signed char* __restrict__ B0,
                                                 const signed char* __restrict__ B1,
                                                 unsigned short* __restrict__ dh,
                                                 const float* __restrict__ asx,
                                                 const float* __restrict__ wsc,
                                                 const float* __restrict__ qn,
                                                 const float* __restrict__ kn,
                                                 const float* __restrict__ cs,
                                                 const float* __restrict__ sn,
                                                 unsigned short* __restrict__ qf,
                                                 unsigned short* __restrict__ kf) {
  const int K = HH;
  __shared__ signed char As[2][16384];   // [buf][128][128] swizzled rows
  __shared__ signed char Bs[2][16384];
  int tid = threadIdx.x;
  int wave = tid >> 6, lane = tid & 63, l15 = lane & 15, g = lane >> 4;
  int wm = wave >> 1, wn = wave & 1;

  int gid = (blockIdx.x & 7) * 64 + (blockIdx.x >> 3);   // XCD chunk, 512 blocks
  const signed char *Ap, *Bp;
  int bm, bn, mode;
  if (gid < 384) { mode = 0; bm = (gid / 24) * 128; bn = (gid % 24) * 128; Ap = A0; Bp = B0; }
  else { mode = 1; int vid = gid - 384; bm = (vid >> 4) * 128; bn = (vid & 15) * 128; Ap = B1; Bp = A0; }

#define GSTAGE(K0, BUF)                                                               \
  {                                                                                   \
    _Pragma("unroll")                                                                 \
    for (int r = 0; r < 4; ++r) {                                                     \
      int c = r * 256 + tid;                                                          \
      int row = c >> 3;                                                               \
      int kk2 = ((c & 7) << 4) ^ ((row & 7) << 4);                                    \
      GLD_LDS16(Ap + (size_t)(bm + row) * K + (K0) + kk2, As[BUF] + c * 16);          \
      GLD_LDS16(Bp + (size_t)(bn + row) * K + (K0) + kk2, Bs[BUF] + c * 16);          \
    }                                                                                 \
  }

  int4v acc[4][4] = {};
  GSTAGE(0, 0);
  asm volatile("s_waitcnt vmcnt(0)" ::: "memory");
  __builtin_amdgcn_s_barrier();
  __builtin_amdgcn_sched_barrier(0);

  int buf = 0;
  for (int k0 = 0; k0 < K; k0 += 128) {
    bool more = (k0 + 128 < K);
    if (more) GSTAGE(k0 + 128, buf ^ 1);   // issued early; compute covers latency
#pragma unroll
    for (int ks = 0; ks < 2; ++ks) {
      int4v af[4], bf[4];
#pragma unroll
      for (int i = 0; i < 4; ++i) {
        int ra = wm * 64 + i * 16 + l15;
        af[i] = *(const int4v*)&As[buf][ra * 128 + ((ks * 64 + g * 16) ^ ((ra & 7) << 4))];
        int rb = (mode == 0) ? (wn * 32 + (i & 1) * 16 + (i >> 1) * 64 + l15)
                             : (wn * 64 + i * 16 + l15);
        bf[i] = *(const int4v*)&Bs[buf][rb * 128 + ((ks * 64 + g * 16) ^ ((rb & 7) << 4))];
      }
      __builtin_amdgcn_s_setprio(1);
#pragma unroll
      for (int mi = 0; mi < 4; ++mi)
#pragma unroll
        for (int ni = 0; ni < 4; ++ni)
          acc[mi][ni] = __builtin_amdgcn_mfma_i32_16x16x64_i8(af[mi], bf[ni], acc[mi][ni], 0, 0, 0);
      __builtin_amdgcn_s_setprio(0);
    }
    asm volatile("s_waitcnt vmcnt(0)" ::: "memory");
    __builtin_amdgcn_s_barrier();
    __builtin_amdgcn_sched_barrier(0);
    buf ^= 1;
  }
#undef GSTAGE

  if (mode == 0) {
    // fused rmsnorm + rope epilogue -> single fp16
    bool isq = (bn < 2048);
    int hh = isq ? (bn >> 7) : ((bn - 2048) >> 7);
    float wN = isq ? wsc[0] : wsc[1];
    float ps = isq ? 0.12751743075f : 1.0f;   // (1/sqrt(128))*log2(e) for q
    const float* nw = isq ? qn : kn;
    unsigned short* oh = isq ? qf : kf;
    int nhp = isq ? NHQ : NKVH;
    float* S = (float*)&As[0][0];        // reuse LDS: [2][128] f32
    __syncthreads();
#pragma unroll
    for (int mi = 0; mi < 4; ++mi) {
#pragma unroll
      for (int rr = 0; rr < 4; ++rr) {
        int tok = bm + wm * 64 + mi * 16 + 4 * g + rr;
        float rs = asx[tok] * wN;
        float ssum = 0.f;
#pragma unroll
        for (int ni = 0; ni < 4; ++ni) {
          float v = (float)acc[mi][ni][rr] * rs;
          ssum += v * v;
        }
        ssum += __shfl_xor(ssum, 1); ssum += __shfl_xor(ssum, 2);
        ssum += __shfl_xor(ssum, 4); ssum += __shfl_xor(ssum, 8);
        if (l15 == 0) S[wn * 128 + wm * 64 + mi * 16 + 4 * g + rr] = ssum;
      }
    }
    __syncthreads();
#pragma unroll
    for (int mi = 0; mi < 4; ++mi) {
#pragma unroll
      for (int rr = 0; rr < 4; ++rr) {
        int rloc = wm * 64 + mi * 16 + 4 * g + rr;
        int tok = bm + rloc;
        float rs = asx[tok] * wN;
        float inv = rsqrtf((S[rloc] + S[128 + rloc]) * (1.f / 128.f) + 1e-6f);
        int s = tok & (SEQ - 1);
        float nv[4];
#pragma unroll
        for (int ni = 0; ni < 4; ++ni) {
          int d = wn * 32 + (ni & 1) * 16 + (ni >> 1) * 64 + l15;
          nv[ni] = nw[d] * ((float)acc[mi][ni][rr] * rs) * inv;
        }
#pragma unroll
        for (int ni = 0; ni < 4; ++ni) {
          int d = wn * 32 + (ni & 1) * 16 + (ni >> 1) * 64 + l15;
          float oo = nv[ni ^ 2];
          float rh = (ni < 2) ? -oo : oo;
          float res = (nv[ni] * cs[s * 128 + d] + rh * sn[s * 128 + d]) * ps;
          size_t oi = ((size_t)tok * nhp + hh) * 128 + d;
          oh[oi] = f2h(res);
        }
      }
    }
  } else {   // mode 1: V fp16 transposed (crow=feature, ccol=token)
    float w2 = wsc[2];
#pragma unroll
    for (int mi = 0; mi < 4; ++mi) {
#pragma unroll
      for (int rr = 0; rr < 4; ++rr) {
        int crow = bm + wm * 64 + mi * 16 + 4 * g + rr;
#pragma unroll
        for (int ni = 0; ni < 4; ++ni) {
          int ccol = bn + wn * 64 + ni * 16 + l15;
          float v = (float)acc[mi][ni][rr] * asx[ccol] * w2;
          size_t ad = ((size_t)((ccol >> 10) * 1024 + crow)) * 1024 + (ccol & 1023);
          dh[ad] = f2h(v);
        }
      }
    }
  }
}

// ---------------------------------------------------------------------------
// K4b: O projection, 128x64 tiles, BK=128, 512 blocks, 2-buffer pipeline.
// ---------------------------------------------------------------------------
__global__ __launch_bounds__(256) void k_gemm_o(const signed char* __restrict__ A,
                                                const signed char* __restrict__ B,
                                                float* __restrict__ d0,
                                                const float* __restrict__ asx,
                                                const float* __restrict__ wsc) {
  const int K = HH;
  __shared__ signed char As[2][16384];   // [buf][128][128]
  __shared__ signed char Bs[2][8192];    // [buf][64][128]
  int tid = threadIdx.x;
  int wave = tid >> 6, lane = tid & 63, l15 = lane & 15, g = lane >> 4;
  int gid = (blockIdx.x & 7) * 64 + (blockIdx.x >> 3);
  int bm = (gid >> 5) * 128, bn = (gid & 31) * 64;

#define OSTAGE(K0, BUF)                                                               \
  {                                                                                   \
    _Pragma("unroll")                                                                 \
    for (int r = 0; r < 4; ++r) {                                                     \
      int c = r * 256 + tid;                                                          \
      int row = c >> 3;                                                               \
      int kk2 = ((c & 7) << 4) ^ ((row & 7) << 4);                                    \
      GLD_LDS16(A + (size_t)(bm + row) * K + (K0) + kk2, As[BUF] + c * 16);           \
    }                                                                                 \
    _Pragma("unroll")                                                                 \
    for (int r = 0; r < 2; ++r) {                                                     \
      int c = r * 256 + tid;                                                          \
      int row = c >> 3;                                                               \
      int kk2 = ((c & 7) << 4) ^ ((row & 7) << 4);                                    \
      GLD_LDS16(B + (size_t)(bn + row) * K + (K0) + kk2, Bs[BUF] + c * 16);           \
    }                                                                                 \
  }

  int4v acc[2][4] = {};
  OSTAGE(0, 0);
  asm volatile("s_waitcnt vmcnt(0)" ::: "memory");
  __builtin_amdgcn_s_barrier();
  __builtin_amdgcn_sched_barrier(0);

  int buf = 0;
  for (int k0 = 0; k0 < K; k0 += 128) {
    bool more = (k0 + 128 < K);
    if (more) OSTAGE(k0 + 128, buf ^ 1);
#pragma unroll
    for (int ks = 0; ks < 2; ++ks) {
      int4v af[2], bf[4];
#pragma unroll
      for (int i = 0; i < 2; ++i) {
        int ra = wave * 32 + i * 16 + l15;
        af[i] = *(const int4v*)&As[buf][ra * 128 + ((ks * 64 + g * 16) ^ ((ra & 7) << 4))];
      }
#pragma unroll
      for (int n = 0; n < 4; ++n) {
        int rb = n * 16 + l15;
        bf[n] = *(const int4v*)&Bs[buf][rb * 128 + ((ks * 64 + g * 16) ^ ((rb & 7) << 4))];
      }
      __builtin_amdgcn_s_setprio(1);
#pragma unroll
      for (int mi = 0; mi < 2; ++mi)
#pragma unroll
        for (int ni = 0; ni < 4; ++ni)
          acc[mi][ni] = __builtin_amdgcn_mfma_i32_16x16x64_i8(af[mi], bf[ni], acc[mi][ni], 0, 0, 0);
      __builtin_amdgcn_s_setprio(0);
    }
    asm volatile("s_waitcnt vmcnt(0)" ::: "memory");
    __builtin_amdgcn_s_barrier();
    __builtin_amdgcn_sched_barrier(0);
    buf ^= 1;
  }
#undef OSTAGE

  float w3 = wsc[3];
#pragma unroll
  for (int mi = 0; mi < 2; ++mi) {
#pragma unroll
    for (int rr = 0; rr < 4; ++rr) {
      int crow = bm + wave * 32 + mi * 16 + 4 * g + rr;
      float rs = asx[crow] * w3;
#pragma unroll
      for (int ni = 0; ni < 4; ++ni) {
        int ccol = bn + ni * 16 + l15;
        d0[(size_t)crow * 2048 + ccol] = (float)acc[mi][ni][rr] * rs;
      }
    }
  }
}

// ---------------------------------------------------------------------------
// K5: per-row act_quant of fp16 attn out -> int8 (ushort8 loads)
// ---------------------------------------------------------------------------
__global__ __launch_bounds__(256) void k_actquant(const unsigned short* __restrict__ x,
                                                  signed char* __restrict__ xq,
                                                  float* __restrict__ as_inv) {
  int row = blockIdx.x, tid = threadIdx.x;
  int wave = tid >> 6, lane = tid & 63;
  short8 raw = ((const short8*)(x + (size_t)row * HH))[tid];
  float vals[8];
#pragma unroll
  for (int j = 0; j < 8; ++j) vals[j] = h2f((unsigned short)raw[j]);
  float am = 0.f;
#pragma unroll
  for (int j = 0; j < 8; ++j) am = fmaxf(am, fabsf(vals[j]));
#pragma unroll
  for (int o = 32; o; o >>= 1) am = fmaxf(am, __shfl_xor(am, o));
  __shared__ float wred[4];
  if (lane == 0) wred[wave] = am;
  __syncthreads();
  am = fmaxf(fmaxf(wred[0], wred[1]), fmaxf(wred[2], wred[3]));
  am = fmaxf(am, 1e-5f);
  if (tid == 0) as_inv[row] = am / 127.f;
  float scale = 127.f / am;
  unsigned int u0 = 0, u1 = 0;
#pragma unroll
  for (int j = 0; j < 4; ++j) {
    int q = (int)fminf(fmaxf(rintf(vals[j] * scale), -128.f), 127.f);
    u0 |= (unsigned int)(q & 255) << (8 * j);
  }
#pragma unroll
  for (int j = 0; j < 4; ++j) {
    int q = (int)fminf(fmaxf(rintf(vals[4 + j] * scale), -128.f), 127.f);
    u1 |= (unsigned int)(q & 255) << (8 * j);
  }
  uint2 uu; uu.x = u0; uu.y = u1;
  ((uint2*)(xq + (size_t)row * HH))[tid] = uu;
}

// ---------------------------------------------------------------------------
// K6: MFMA flash attention, KV tile 64, 2-buffer stage-at-top pipeline,
// balanced CU pairing. fp16 output. Hosts wot quant in blocks 512..639
// (overlaps the attention window, where HBM is nearly idle).
// ---------------------------------------------------------------------------
__global__ __launch_bounds__(256) void k_attn_mfma(const unsigned short* __restrict__ qfp,
                                                   const unsigned short* __restrict__ kfp,
                                                   const unsigned short* __restrict__ vfp,
                                                   unsigned short* __restrict__ o,
                                                   const float* __restrict__ wsc,
                                                   const float* __restrict__ wo_f32,
                                                   signed char* __restrict__ wot) {
  int tid = threadIdx.x;
  if (blockIdx.x >= 512) {
    int bx = blockIdx.x - 512;          // 0..127
    float inv = 1.f / wsc[3];
    for (int qi = bx * 256 + tid; qi < 1048576; qi += 128 * 256) {
      float4 v = ((const float4*)wo_f32)[qi];
      unsigned int u = 0;
      float vv[4] = {v.x, v.y, v.z, v.w};
#pragma unroll
      for (int j = 0; j < 4; ++j) {
        int q = (int)fminf(fmaxf(rintf(vv[j] * inv), -1.f), 1.f);
        u |= (unsigned int)(q & 255) << (8 * j);
      }
      ((unsigned int*)wot)[qi] = u;
    }
    return;
  }

  int chunk = blockIdx.x & 7, j = blockIdx.x >> 3;   // XCD, within-chunk
  int qt, yyi;
  if (j < 32) { qt = 15 - (j >> 2); yyi = j & 3; }          // heavy half first
  else        { qt = (j - 32) >> 2; yyi = (j - 32) & 3; }   // paired light half
  int yy = (chunk << 2) + yyi;
  int b = yy >> 4, h = yy & 15, kvh = h >> 1;
  int wave = tid >> 6, lane = tid & 63;
  int l15 = lane & 15, g = lane >> 4;
  int q0w = qt * 64 + wave * 16;
  int qglob = q0w + l15;

  __shared__ unsigned short Kf[2][8192];     // fp16 K, [ki(64)][d(128)] swizzled
  __shared__ unsigned short Vf[2][8192];     // fp16 V^T [d(128)][tok(64)] swizzled
  __shared__ unsigned short Plds[4][16][72]; // fp16 P, 64 keys + pad

  half8 qf[4];
  {
    const unsigned short* qb = qfp + ((size_t)(b * SEQ + qglob) * NHQ + h) * HDD + g * 8;
#pragma unroll
    for (int c = 0; c < 4; ++c) qf[c] = s2h(*(const short8*)(qb + c * 32));
  }
  half8 vones;
#pragma unroll
  for (int c = 0; c < 8; ++c) vones[c] = (_Float16)1.0f;

#define STAGE64(KV0N, BUF)                                                            \
  {                                                                                   \
    _Pragma("unroll")                                                                 \
    for (int tch = 0; tch < 4; ++tch) {                                               \
      int c = tch * 256 + tid;                                                        \
      int ki = c >> 4, jb = (c & 15) << 4;                                            \
      int js = jb ^ ((ki & 7) << 4);                                                  \
      size_t kbase = ((size_t)(b * SEQ + (KV0N) + ki) * NKVH + kvh) * HDD;            \
      GLD_LDS16((const char*)(kfp + kbase) + js, &Kf[BUF][c * 8]);                    \
      int d = c >> 3, jv = (c & 7) << 4;                                              \
      int jvs = jv ^ ((d & 7) << 4);                                                  \
      size_t vbase = ((size_t)(b * 1024 + kvh * 128 + d)) * SEQ + (KV0N);             \
      GLD_LDS16((const char*)(vfp + vbase) + jvs, &Vf[BUF][c * 8]);                   \
    }                                                                                 \
  }

  f32x4 acc[9] = {};                 // [0..7]=O d-tiles, [8]=l (ones-V)
  float m_run = -INFINITY;
  int nkv = qt + 1;                  // 64-key tiles

  STAGE64(0, 0);
  asm volatile("s_waitcnt vmcnt(0) lgkmcnt(0)" ::: "memory");
  __builtin_amdgcn_s_barrier();
  __builtin_amdgcn_sched_barrier(0);

  int buf = 0;
  for (int kv = 0; kv < nkv; ++kv) {
    int kv0 = kv * 64;
    bool more = (kv + 1 < nkv);
    if (more) STAGE64(kv0 + 64, buf ^ 1);   // issued early; compute covers latency
    bool active = (kv0 <= q0w + 15);
    if (active) {
      const char* Kb = (const char*)&Kf[buf][0];
      const char* Vb = (const char*)&Vf[buf][0];
      // ---- QK^T (fp16, scores in log2 units): 4 tiles of 16 keys ----
      float sc[4][4];
      __builtin_amdgcn_s_setprio(1);
#pragma unroll
      for (int t = 0; t < 4; ++t) {
        int row = 16 * t + l15;
        int rbyte = row * 256, sw = (row & 7) << 4;
        f32x4 s = {0.f, 0.f, 0.f, 0.f};
#pragma unroll
        for (int c = 0; c < 4; ++c) {
          int off = rbyte + ((c * 64 + g * 16) ^ sw);
          half8 kf8 = s2h(*(const short8*)(Kb + off));
          s = __builtin_amdgcn_mfma_f32_16x16x32_f16(kf8, qf[c], s, 0, 0, 0);
        }
#pragma unroll
        for (int r = 0; r < 4; ++r) sc[t][r] = s[r];
      }
      __builtin_amdgcn_s_setprio(0);
      if (kv0 + 63 > q0w) {
#pragma unroll
        for (int t = 0; t < 4; ++t)
#pragma unroll
          for (int r = 0; r < 4; ++r)
            if (kv0 + 16 * t + 4 * g + r > qglob) sc[t][r] = -INFINITY;
      }
      // ---- online softmax (exp2; defer-max, per-lane check) ----
      float pmax = -INFINITY;
#pragma unroll
      for (int t = 0; t < 4; ++t)
#pragma unroll
        for (int r = 0; r < 4; ++r) pmax = fmaxf(pmax, sc[t][r]);
      if (!__all(pmax <= m_run + 10.f)) {
        pmax = fmaxf(pmax, __shfl_xor(pmax, 16));
        pmax = fmaxf(pmax, __shfl_xor(pmax, 32));
        float mnew = fmaxf(m_run, pmax);
        float corr = exp2f(m_run - mnew);
        m_run = mnew;
        float corro[4];
#pragma unroll
        for (int r = 0; r < 4; ++r) corro[r] = __shfl(corr, 4 * g + r);
#pragma unroll
        for (int dt = 0; dt < 9; ++dt)
#pragma unroll
          for (int r = 0; r < 4; ++r) acc[dt][r] *= corro[r];
      }
      // ---- P -> fp16, transpose through per-wave LDS ----
      ushort4 wh;
#pragma unroll
      for (int t = 0; t < 4; ++t) {
        wh.x = f2h(exp2f(sc[t][0] - m_run));
        wh.y = f2h(exp2f(sc[t][1] - m_run));
        wh.z = f2h(exp2f(sc[t][2] - m_run));
        wh.w = f2h(exp2f(sc[t][3] - m_run));
        *(ushort4*)&Plds[wave][l15][16 * t + 4 * g] = wh;
      }
      half8 pa0 = s2h(*(const short8*)&Plds[wave][l15][8 * g]);
      half8 pa1 = s2h(*(const short8*)&Plds[wave][l15][32 + 8 * g]);
      // ---- PV (fp16): 2 k-halves per d-tile + l via constant-ones ----
      __builtin_amdgcn_s_setprio(1);
#pragma unroll
      for (int dt = 0; dt < 8; ++dt) {
        int d = dt * 16 + l15;
        int rbase = d * 128, sw = (d & 7) << 4;
        half8 v0 = s2h(*(const short8*)(Vb + rbase + ((g * 16) ^ sw)));
        half8 v1 = s2h(*(const short8*)(Vb + rbase + ((64 + g * 16) ^ sw)));
        acc[dt] = __builtin_amdgcn_mfma_f32_16x16x32_f16(pa0, v0, acc[dt], 0, 0, 0);
        acc[dt] = __builtin_amdgcn_mfma_f32_16x16x32_f16(pa1, v1, acc[dt], 0, 0, 0);
      }
      acc[8] = __builtin_amdgcn_mfma_f32_16x16x32_f16(pa0, vones, acc[8], 0, 0, 0);
      acc[8] = __builtin_amdgcn_mfma_f32_16x16x32_f16(pa1, vones, acc[8], 0, 0, 0);
      __builtin_amdgcn_s_setprio(0);
    }
    asm volatile("s_waitcnt vmcnt(0)" ::: "memory");   // next buf landed (covered)
    __builtin_amdgcn_s_barrier();
    __builtin_amdgcn_sched_barrier(0);
    buf ^= 1;
  }
#undef STAGE64

  float linv[4];
#pragma unroll
  for (int r = 0; r < 4; ++r) linv[r] = 1.f / acc[8][r];
#pragma unroll
  for (int r = 0; r < 4; ++r) {
    size_t orow = ((size_t)(b * SEQ + q0w + 4 * g + r) * NHQ + h) * HDD + l15;
#pragma unroll
    for (int dt = 0; dt < 8; ++dt)
      o[orow + dt * 16] = f2h(acc[dt][r] * linv[r]);
  }
}

// ---------------------------------------------------------------------------
extern "C" void kernel_launch(void* const* d_in, const int* in_sizes, int n_in,
                              void* d_out, int out_size, void* d_ws, size_t ws_size,
                              hipStream_t stream) {
  const float* x  = (const float*)d_in[0];
  const float* cs = (const float*)d_in[1];
  const float* sn = (const float*)d_in[2];
  const float* wq = (const float*)d_in[3];
  const float* wk = (const float*)d_in[4];
  const float* wv = (const float*)d_in[5];
  const float* wo = (const float*)d_in[6];
  const float* qn = (const float*)d_in[7];
  const float* kn = (const float*)d_in[8];
  float* out = (float*)d_out;
  char* ws = (char*)d_ws;

  const size_t MB = 1024 * 1024;
  size_t o_xq  = 0;            // 4 MB  int8 xq
  size_t o_wqk = 4  * MB;      // 6 MB  [3072][2048] i8
  size_t o_wvt = 10 * MB;      // 2 MB  [1024][2048] i8
  size_t o_wot = 12 * MB;      // 4 MB  [2048][2048] i8
  size_t o_vt  = 16 * MB;      // 4 MB  fp16 V transposed
  size_t o_qf  = 20 * MB;      // 8 MB  fp16 q (rope'd, log2e/sqrt(128) folded)
  size_t o_kf  = 28 * MB;      // 4 MB  fp16 k (rope'd)
  size_t o_ao  = 32 * MB;      // 8 MB  fp16 attn out
  size_t o_aq  = 40 * MB;      // 4 MB  int8 requant
  size_t o_as  = 44 * MB;
  size_t o_as2 = o_as  + 8192;
  size_t o_prt = o_as2 + 8192;
  size_t o_wsc = o_prt + 8192;

  signed char* xq  = (signed char*)(ws + o_xq);
  signed char* wqk = (signed char*)(ws + o_wqk);
  signed char* wvt = (signed char*)(ws + o_wvt);
  signed char* wot = (signed char*)(ws + o_wot);
  unsigned short* vt = (unsigned short*)(ws + o_vt);
  unsigned short* qf = (unsigned short*)(ws + o_qf);
  unsigned short* kf = (unsigned short*)(ws + o_kf);
  unsigned short* ao = (unsigned short*)(ws + o_ao);
  signed char* aq = (signed char*)(ws + o_aq);
  float* asx = (float*)(ws + o_as);
  float* as2 = (float*)(ws + o_as2);
  double* prt = (double*)(ws + o_prt);
  float* wsc = (float*)(ws + o_wsc);

  // 1) act quant of x + weight |w| partials (one dispatch)
  k_quant_stats<<<3072, 256, 0, stream>>>(x, xq, asx, wq, wk, wv, wo, prt);

  // 2) ternary quant of wq/wk/wv (publishes wsc)
  k_wquant_all<<<1024, 256, 0, stream>>>(wq, wk, wv, wqk, wvt, prt, wsc);

  // 3) fused QKV projection + rmsnorm/rope epilogue (128x128, BK=128)
  k_gemm_i8<<<512, 256, 0, stream>>>(xq, wqk, wvt, vt, asx, wsc,
                                     qn, kn, cs, sn, qf, kf);

  // 4) MFMA flash attention (KV tile 64, fp16 out) + overlapped wot quant
  k_attn_mfma<<<640, 256, 0, stream>>>(qf, kf, vt, ao, wsc, wo, wot);

  // 5) re-quant (fp16 in) + output projection (128x64, BK=128)
  k_actquant<<<TT, 256, 0, stream>>>(ao, aq, as2);
  k_gemm_o<<<512, 256, 0, stream>>>(aq, wot, out, as2, wsc);
}